// Round 1
// baseline (4345.668 us; speedup 1.0000x reference)
//
#include <hip/hip_runtime.h>
#include <math.h>

// ChildSumTreeLSTM on a perfect binary tree (heap node indexing).
// B=8, L=16384 leaves, N=2L-1=32767 nodes, D_IN=D_H=256.
// Round 1: correctness-first fp32. hbuf/cbuf hold h,c for ALL nodes
// (node g's children = 2g+1, 2g+2). Leaf kernel + 14 sequential level
// kernels + output gather. GEMMs are register-tiled dot products:
// one output column per thread, R rows/block staged in LDS (broadcast
// reads), weights streamed (L2-resident, 2.1 MB total).

#define Bb 8
#define Lleaf 16384
#define Nn 32767
#define Dd 256

__device__ __forceinline__ float sigf(float x) {
    return __builtin_amdgcn_rcpf(1.0f + __expf(-x));
}
__device__ __forceinline__ float tanh_fast(float x) {
    // tanh(x) = 2*sigmoid(2x) - 1
    return fmaf(2.0f, sigf(2.0f * x), -1.0f);
}

// ---------------- leaf level: iou = x_leaf @ W_iou + b_iou -----------------
__global__ __launch_bounds__(256) void leaf_kernel(
    const float* __restrict__ x, const float* __restrict__ W_iou,
    const float* __restrict__ b_iou,
    float* __restrict__ hbuf, float* __restrict__ cbuf)
{
    const int R = 16;
    __shared__ float xs[R][Dd];
    const int t = threadIdx.x;
    // 16 consecutive leaf rows; L % 16 == 0 so a block stays in one batch.
    const int m0 = blockIdx.x * R;           // global leaf-row id [0, B*L)
    const int b  = m0 / Lleaf;
    const int j0 = m0 % Lleaf;
    const int base = (b * Nn + (Lleaf - 1) + j0) * Dd;   // < 2^27, fits int

    #pragma unroll
    for (int r = 0; r < R; ++r)
        xs[r][t] = x[base + r * Dd + t];
    __syncthreads();

    float ai[R], ao[R], au[R];
    {
        const float bi = b_iou[t], bo = b_iou[256 + t], bu = b_iou[512 + t];
        #pragma unroll
        for (int r = 0; r < R; ++r) { ai[r] = bi; ao[r] = bo; au[r] = bu; }
    }
    for (int k = 0; k < Dd; ++k) {
        const float wi = W_iou[k * 768 + t];
        const float wo = W_iou[k * 768 + 256 + t];
        const float wu = W_iou[k * 768 + 512 + t];
        #pragma unroll
        for (int r = 0; r < R; ++r) {
            const float xk = xs[r][k];      // wave-broadcast LDS read
            ai[r] = fmaf(xk, wi, ai[r]);
            ao[r] = fmaf(xk, wo, ao[r]);
            au[r] = fmaf(xk, wu, au[r]);
        }
    }
    #pragma unroll
    for (int r = 0; r < R; ++r) {
        const float c = sigf(ai[r]) * tanh_fast(au[r]);
        const float h = sigf(ao[r]) * tanh_fast(c);
        hbuf[base + r * Dd + t] = h;
        cbuf[base + r * Dd + t] = c;
    }
}

// ---------------- internal level with n nodes per batch --------------------
__global__ __launch_bounds__(256) void level_kernel(
    const float* __restrict__ x,
    const float* __restrict__ W_iou, const float* __restrict__ b_iou,
    const float* __restrict__ U_iou,
    const float* __restrict__ W_f,   const float* __restrict__ b_f,
    const float* __restrict__ U_f,
    float* __restrict__ hbuf, float* __restrict__ cbuf, int n)
{
    const int R = 8;   // B*n is always divisible by 8 (B=8) -> no tail
    __shared__ float xs[R][Dd], h1s[R][Dd], h2s[R][Dd];
    const int t = threadIdx.x;

    int rowbase[R], c1base[R], c2base[R];
    #pragma unroll
    for (int r = 0; r < R; ++r) {
        const int m = blockIdx.x * R + r;    // row id in [0, B*n)
        const int b = m / n, j = m % n;
        const int g = n - 1 + j;             // global node index
        const int nb = b * Nn;
        rowbase[r] = (nb + g) * Dd;
        c1base[r]  = (nb + 2 * g + 1) * Dd;
        c2base[r]  = (nb + 2 * g + 2) * Dd;
        xs[r][t]  = x[rowbase[r] + t];
        h1s[r][t] = hbuf[c1base[r] + t];
        h2s[r][t] = hbuf[c2base[r] + t];
    }
    __syncthreads();

    float ai[R], ao[R], au[R], fx[R], g1[R], g2[R];
    {
        const float bi = b_iou[t], bo = b_iou[256 + t], bu = b_iou[512 + t];
        const float bf = b_f[t];
        #pragma unroll
        for (int r = 0; r < R; ++r) {
            ai[r] = bi; ao[r] = bo; au[r] = bu;
            fx[r] = bf; g1[r] = 0.f; g2[r] = 0.f;
        }
    }
    for (int k = 0; k < Dd; ++k) {
        const float wi = W_iou[k * 768 + t];
        const float wo = W_iou[k * 768 + 256 + t];
        const float wu = W_iou[k * 768 + 512 + t];
        const float ui = U_iou[k * 768 + t];
        const float uo = U_iou[k * 768 + 256 + t];
        const float uu = U_iou[k * 768 + 512 + t];
        const float wf = W_f[k * 256 + t];
        const float uf = U_f[k * 256 + t];
        #pragma unroll
        for (int r = 0; r < R; ++r) {
            const float xk = xs[r][k], h1k = h1s[r][k], h2k = h2s[r][k];
            const float hs = h1k + h2k;
            ai[r] = fmaf(xk, wi, ai[r]); ai[r] = fmaf(hs, ui, ai[r]);
            ao[r] = fmaf(xk, wo, ao[r]); ao[r] = fmaf(hs, uo, ao[r]);
            au[r] = fmaf(xk, wu, au[r]); au[r] = fmaf(hs, uu, au[r]);
            fx[r] = fmaf(xk, wf, fx[r]);
            g1[r] = fmaf(h1k, uf, g1[r]);
            g2[r] = fmaf(h2k, uf, g2[r]);
        }
    }
    #pragma unroll
    for (int r = 0; r < R; ++r) {
        const float f1 = sigf(fx[r] + g1[r]);
        const float f2 = sigf(fx[r] + g2[r]);
        const float c1 = cbuf[c1base[r] + t];
        const float c2 = cbuf[c2base[r] + t];
        const float c  = sigf(ai[r]) * tanh_fast(au[r]) + f1 * c1 + f2 * c2;
        const float h  = sigf(ao[r]) * tanh_fast(c);
        hbuf[rowbase[r] + t] = h;
        cbuf[rowbase[r] + t] = c;
    }
}

// ---------------- gather root h,c -> out (B, 512) --------------------------
__global__ __launch_bounds__(256) void out_kernel(
    const float* __restrict__ hbuf, const float* __restrict__ cbuf,
    float* __restrict__ out)
{
    const int t = threadIdx.x;
    const int b = blockIdx.x;
    out[b * 512 + t]       = hbuf[(b * Nn) * Dd + t];  // root node g=0
    out[b * 512 + 256 + t] = cbuf[(b * Nn) * Dd + t];
}

extern "C" void kernel_launch(void* const* d_in, const int* in_sizes, int n_in,
                              void* d_out, int out_size, void* d_ws, size_t ws_size,
                              hipStream_t stream) {
    const float* x     = (const float*)d_in[0];
    const float* W_iou = (const float*)d_in[1];
    const float* b_iou = (const float*)d_in[2];
    const float* U_iou = (const float*)d_in[3];
    const float* W_f   = (const float*)d_in[4];
    const float* b_f   = (const float*)d_in[5];
    const float* U_f   = (const float*)d_in[6];
    float* out = (float*)d_out;

    float* hbuf = (float*)d_ws;                         // B*N*D floats
    float* cbuf = hbuf + (size_t)Bb * Nn * Dd;          // B*N*D floats
    // total ws use: 2 * 8 * 32767 * 256 * 4 B ~= 537 MB

    leaf_kernel<<<(Bb * Lleaf) / 16, 256, 0, stream>>>(x, W_iou, b_iou, hbuf, cbuf);
    for (int n = Lleaf / 2; n >= 1; n >>= 1) {
        level_kernel<<<n /* = B*n/8 */, 256, 0, stream>>>(
            x, W_iou, b_iou, U_iou, W_f, b_f, U_f, hbuf, cbuf, n);
    }
    out_kernel<<<Bb, 256, 0, stream>>>(hbuf, cbuf, out);
}

// Round 2
// 1695.934 us; speedup vs baseline: 2.5624x; 2.5624x over previous
//
#include <hip/hip_runtime.h>
#include <math.h>

// ChildSumTreeLSTM, round 2: bf16 MFMA GEMM per tree level.
// A = [x | h1 | h2] (K=768), Bt = packed/permuted weights [1280][768] (K-major),
// columns gate-interleaved: col' = 80*q + 16*g + r, q=h-dim group of 16,
// g in {i,o,u,f1,f2}. A 160-col tile holds all 5 gates for 32 h-dims ->
// LSTM epilogue fused into the GEMM block. h stored bf16, c stored fp32.
// Leaf: K=256, 3 gates, col' = 48*q + 16*g + r. Levels n<=8: fp32 fallback.

#define Bb 8
#define Lleaf 16384
#define Nn 32767
#define Dd 256

typedef __attribute__((ext_vector_type(8))) short short8;
typedef __attribute__((ext_vector_type(4))) float float4v;

__device__ __forceinline__ float sigf(float x) {
    return __builtin_amdgcn_rcpf(1.0f + __expf(-x));
}
__device__ __forceinline__ float tanh_fast(float x) {
    return fmaf(2.0f, sigf(2.0f * x), -1.0f);
}
__device__ __forceinline__ unsigned short f2bf(float f) {
    unsigned int u = __float_as_uint(f);
    u = (u + 0x7FFFu + ((u >> 16) & 1u)) >> 16;   // RTNE, finite inputs
    return (unsigned short)u;
}
__device__ __forceinline__ float bf2f(unsigned short h) {
    return __uint_as_float(((unsigned int)h) << 16);
}

// ---------------- weight packing (once per call, ~2 MB) --------------------
__global__ __launch_bounds__(256) void pack_internal(
    const float* __restrict__ W_iou, const float* __restrict__ U_iou,
    const float* __restrict__ W_f,   const float* __restrict__ U_f,
    unsigned short* __restrict__ Bt)
{
    const int idx = blockIdx.x * 256 + threadIdx.x;      // < 1280*768
    const int col = idx / 768, k = idx - col * 768;
    const int q = col / 80, rem = col - q * 80;
    const int g = rem >> 4, r = rem & 15;
    const int d = (q << 4) + r;
    const int seg = k >> 8, kk = k & 255;
    float val;
    if (g < 3) {
        val = (seg == 0) ? W_iou[kk * 768 + g * 256 + d]
                         : U_iou[kk * 768 + g * 256 + d];
    } else if (seg == 0) {
        val = W_f[kk * 256 + d];
    } else if (seg == 1) {
        val = (g == 3) ? U_f[kk * 256 + d] : 0.0f;
    } else {
        val = (g == 4) ? U_f[kk * 256 + d] : 0.0f;
    }
    Bt[idx] = f2bf(val);
}

__global__ __launch_bounds__(256) void pack_leaf(
    const float* __restrict__ W_iou, unsigned short* __restrict__ Btl)
{
    const int idx = blockIdx.x * 256 + threadIdx.x;      // < 768*256
    const int col = idx >> 8, k = idx & 255;
    const int q = col / 48, rem = col - q * 48;
    const int g = rem >> 4, r = rem & 15;
    const int d = (q << 4) + r;
    Btl[idx] = f2bf(W_iou[k * 768 + g * 256 + d]);
}

// ---------------- internal level MFMA GEMM ---------------------------------
// grid (8n/128, 8); tile M=128, N=160 (2 q-groups), K=768, BK=64.
__global__ __launch_bounds__(256) void gemm_level(
    const float* __restrict__ x, const unsigned short* __restrict__ Bt,
    const float* __restrict__ b_iou, const float* __restrict__ b_f,
    unsigned short* __restrict__ hbuf, float* __restrict__ cbuf,
    int n, int lvl)
{
    __shared__ unsigned short Alds[128 * 72];   // row stride 72: 2-way banks only
    __shared__ unsigned short Blds[160 * 72];
    const int tid  = threadIdx.x;
    const int wave = tid >> 6, lane = tid & 63;
    const int l16  = lane & 15, q4 = lane >> 4;
    const int m0   = blockIdx.x * 128;
    const int n0   = blockIdx.y * 160;

    float4v acc[2][10];
    #pragma unroll
    for (int qq = 0; qq < 2; ++qq) {
        const int d = ((blockIdx.y * 2 + qq) << 4) + l16;
        float bv0 = b_iou[d], bv1 = b_iou[256 + d], bv2 = b_iou[512 + d];
        float bv3 = b_f[d];
        float bv[5] = {bv0, bv1, bv2, bv3, bv3};
        #pragma unroll
        for (int g = 0; g < 5; ++g) {
            float4v v; v[0] = bv[g]; v[1] = bv[g]; v[2] = bv[g]; v[3] = bv[g];
            acc[0][qq * 5 + g] = v; acc[1][qq * 5 + g] = v;
        }
    }

    for (int kk = 0; kk < 12; ++kk) {          // K segments: 0-3 x, 4-7 h1, 8-11 h2
        __syncthreads();
        {   // stage A: 128 rows x 64 k
            int task = tid;
            #pragma unroll
            for (int it = 0; it < 4; ++it, task += 256) {
                const int r = task >> 3, k8 = task & 7;
                const int m = m0 + r;
                const int b = m >> lvl, j = m & (n - 1);
                const int nb = b * Nn;
                if (kk < 4) {
                    const float4* p = (const float4*)(x +
                        (((nb + n - 1 + j) << 8) + kk * 64 + (k8 << 3)));
                    const float4 f0 = p[0], f1 = p[1];
                    union { unsigned short us[8]; uint4 v; } pk;
                    pk.us[0] = f2bf(f0.x); pk.us[1] = f2bf(f0.y);
                    pk.us[2] = f2bf(f0.z); pk.us[3] = f2bf(f0.w);
                    pk.us[4] = f2bf(f1.x); pk.us[5] = f2bf(f1.y);
                    pk.us[6] = f2bf(f1.z); pk.us[7] = f2bf(f1.w);
                    *(uint4*)&Alds[r * 72 + (k8 << 3)] = pk.v;
                } else {
                    const int child = 2 * n - 1 + 2 * j + (kk >= 8 ? 1 : 0);
                    const int koff = ((kk - 4) & 3) * 64;
                    const uint4 v = *(const uint4*)(hbuf +
                        (((nb + child) << 8) + koff + (k8 << 3)));
                    *(uint4*)&Alds[r * 72 + (k8 << 3)] = v;
                }
            }
        }
        {   // stage B: 160 rows x 64 k
            int task = tid;
            #pragma unroll
            for (int it = 0; it < 5; ++it, task += 256) {
                const int nr = task >> 3, k8 = task & 7;
                const uint4 v = *(const uint4*)(Bt +
                    ((n0 + nr) * 768 + kk * 64 + (k8 << 3)));
                *(uint4*)&Blds[nr * 72 + (k8 << 3)] = v;
            }
        }
        __syncthreads();
        #pragma unroll
        for (int ks = 0; ks < 2; ++ks) {
            const short8 a0 = *(const short8*)&Alds[(wave * 32 + l16) * 72 + ks * 32 + q4 * 8];
            const short8 a1 = *(const short8*)&Alds[(wave * 32 + 16 + l16) * 72 + ks * 32 + q4 * 8];
            #pragma unroll
            for (int ni = 0; ni < 10; ++ni) {
                const short8 bf = *(const short8*)&Blds[(ni * 16 + l16) * 72 + ks * 32 + q4 * 8];
                acc[0][ni] = __builtin_amdgcn_mfma_f32_16x16x32_bf16(a0, bf, acc[0][ni], 0, 0, 0);
                acc[1][ni] = __builtin_amdgcn_mfma_f32_16x16x32_bf16(a1, bf, acc[1][ni], 0, 0, 0);
            }
        }
    }

    // fused LSTM epilogue: C/D row = q4*4+reg, col = l16
    #pragma unroll
    for (int mi = 0; mi < 2; ++mi) {
        #pragma unroll
        for (int reg = 0; reg < 4; ++reg) {
            const int row_l = wave * 32 + mi * 16 + (q4 << 2) + reg;
            const int m = m0 + row_l;
            const int b = m >> lvl, j = m & (n - 1);
            const int nb = b * Nn;
            const int cbase = (nb + 2 * n - 1 + 2 * j) << 8;
            const int obase = (nb + n - 1 + j) << 8;
            #pragma unroll
            for (int qq = 0; qq < 2; ++qq) {
                const int d = ((blockIdx.y * 2 + qq) << 4) + l16;
                const float i_ = acc[mi][qq * 5 + 0][reg];
                const float o_ = acc[mi][qq * 5 + 1][reg];
                const float u_ = acc[mi][qq * 5 + 2][reg];
                const float f1 = acc[mi][qq * 5 + 3][reg];
                const float f2 = acc[mi][qq * 5 + 4][reg];
                const float c1 = cbuf[cbase + d];
                const float c2 = cbuf[cbase + 256 + d];
                const float c = sigf(i_) * tanh_fast(u_) + sigf(f1) * c1 + sigf(f2) * c2;
                const float h = sigf(o_) * tanh_fast(c);
                cbuf[obase + d] = c;
                hbuf[obase + d] = f2bf(h);
            }
        }
    }
}

// ---------------- leaf MFMA GEMM -------------------------------------------
// grid (131072/128, 4); tile M=128, N=192 (4 q-groups), K=256, BK=64.
__global__ __launch_bounds__(256) void gemm_leaf(
    const float* __restrict__ x, const unsigned short* __restrict__ Btl,
    const float* __restrict__ b_iou,
    unsigned short* __restrict__ hbuf, float* __restrict__ cbuf)
{
    __shared__ unsigned short Alds[128 * 72];
    __shared__ unsigned short Blds[192 * 72];
    const int tid  = threadIdx.x;
    const int wave = tid >> 6, lane = tid & 63;
    const int l16  = lane & 15, q4 = lane >> 4;
    const int m0   = blockIdx.x * 128;
    const int n0   = blockIdx.y * 192;

    float4v acc[2][12];
    #pragma unroll
    for (int qq = 0; qq < 4; ++qq) {
        const int d = ((blockIdx.y * 4 + qq) << 4) + l16;
        float bv[3] = {b_iou[d], b_iou[256 + d], b_iou[512 + d]};
        #pragma unroll
        for (int g = 0; g < 3; ++g) {
            float4v v; v[0] = bv[g]; v[1] = bv[g]; v[2] = bv[g]; v[3] = bv[g];
            acc[0][qq * 3 + g] = v; acc[1][qq * 3 + g] = v;
        }
    }

    for (int kk = 0; kk < 4; ++kk) {
        __syncthreads();
        {   // stage A (x only)
            int task = tid;
            #pragma unroll
            for (int it = 0; it < 4; ++it, task += 256) {
                const int r = task >> 3, k8 = task & 7;
                const int m = m0 + r;
                const int b = m >> 14, j = m & (Lleaf - 1);
                const int node = b * Nn + (Lleaf - 1) + j;
                const float4* p = (const float4*)(x + ((node << 8) + kk * 64 + (k8 << 3)));
                const float4 f0 = p[0], f1 = p[1];
                union { unsigned short us[8]; uint4 v; } pk;
                pk.us[0] = f2bf(f0.x); pk.us[1] = f2bf(f0.y);
                pk.us[2] = f2bf(f0.z); pk.us[3] = f2bf(f0.w);
                pk.us[4] = f2bf(f1.x); pk.us[5] = f2bf(f1.y);
                pk.us[6] = f2bf(f1.z); pk.us[7] = f2bf(f1.w);
                *(uint4*)&Alds[r * 72 + (k8 << 3)] = pk.v;
            }
        }
        {   // stage B: 192 rows x 64 k
            int task = tid;
            #pragma unroll
            for (int it = 0; it < 6; ++it, task += 256) {
                const int nr = task >> 3, k8 = task & 7;
                const uint4 v = *(const uint4*)(Btl +
                    ((n0 + nr) * 256 + kk * 64 + (k8 << 3)));
                *(uint4*)&Blds[nr * 72 + (k8 << 3)] = v;
            }
        }
        __syncthreads();
        #pragma unroll
        for (int ks = 0; ks < 2; ++ks) {
            const short8 a0 = *(const short8*)&Alds[(wave * 32 + l16) * 72 + ks * 32 + q4 * 8];
            const short8 a1 = *(const short8*)&Alds[(wave * 32 + 16 + l16) * 72 + ks * 32 + q4 * 8];
            #pragma unroll
            for (int ni = 0; ni < 12; ++ni) {
                const short8 bf = *(const short8*)&Blds[(ni * 16 + l16) * 72 + ks * 32 + q4 * 8];
                acc[0][ni] = __builtin_amdgcn_mfma_f32_16x16x32_bf16(a0, bf, acc[0][ni], 0, 0, 0);
                acc[1][ni] = __builtin_amdgcn_mfma_f32_16x16x32_bf16(a1, bf, acc[1][ni], 0, 0, 0);
            }
        }
    }

    #pragma unroll
    for (int mi = 0; mi < 2; ++mi) {
        #pragma unroll
        for (int reg = 0; reg < 4; ++reg) {
            const int row_l = wave * 32 + mi * 16 + (q4 << 2) + reg;
            const int m = m0 + row_l;
            const int b = m >> 14, j = m & (Lleaf - 1);
            const int obase = (b * Nn + (Lleaf - 1) + j) << 8;
            #pragma unroll
            for (int qq = 0; qq < 4; ++qq) {
                const int d = ((blockIdx.y * 4 + qq) << 4) + l16;
                const float i_ = acc[mi][qq * 3 + 0][reg];
                const float o_ = acc[mi][qq * 3 + 1][reg];
                const float u_ = acc[mi][qq * 3 + 2][reg];
                const float c = sigf(i_) * tanh_fast(u_);
                const float h = sigf(o_) * tanh_fast(c);
                cbuf[obase + d] = c;
                hbuf[obase + d] = f2bf(h);
            }
        }
    }
}

// ---------------- small levels (n<=8): fp32 fallback -----------------------
__global__ __launch_bounds__(256) void level_small(
    const float* __restrict__ x,
    const float* __restrict__ W_iou, const float* __restrict__ b_iou,
    const float* __restrict__ U_iou,
    const float* __restrict__ W_f,   const float* __restrict__ b_f,
    const float* __restrict__ U_f,
    unsigned short* __restrict__ hbuf, float* __restrict__ cbuf, int n)
{
    const int R = 8;
    __shared__ float xs[R][Dd], h1s[R][Dd], h2s[R][Dd];
    const int t = threadIdx.x;

    int rowbase[R], c1base[R], c2base[R];
    #pragma unroll
    for (int r = 0; r < R; ++r) {
        const int m = blockIdx.x * R + r;
        const int b = m / n, j = m % n;
        const int g = n - 1 + j;
        const int nb = b * Nn;
        rowbase[r] = (nb + g) * Dd;
        c1base[r]  = (nb + 2 * g + 1) * Dd;
        c2base[r]  = (nb + 2 * g + 2) * Dd;
        xs[r][t]  = x[rowbase[r] + t];
        h1s[r][t] = bf2f(hbuf[c1base[r] + t]);
        h2s[r][t] = bf2f(hbuf[c2base[r] + t]);
    }
    __syncthreads();

    float ai[R], ao[R], au[R], fx[R], g1[R], g2[R];
    {
        const float bi = b_iou[t], bo = b_iou[256 + t], bu = b_iou[512 + t];
        const float bf = b_f[t];
        #pragma unroll
        for (int r = 0; r < R; ++r) {
            ai[r] = bi; ao[r] = bo; au[r] = bu;
            fx[r] = bf; g1[r] = 0.f; g2[r] = 0.f;
        }
    }
    for (int k = 0; k < Dd; ++k) {
        const float wi = W_iou[k * 768 + t];
        const float wo = W_iou[k * 768 + 256 + t];
        const float wu = W_iou[k * 768 + 512 + t];
        const float ui = U_iou[k * 768 + t];
        const float uo = U_iou[k * 768 + 256 + t];
        const float uu = U_iou[k * 768 + 512 + t];
        const float wf = W_f[k * 256 + t];
        const float uf = U_f[k * 256 + t];
        #pragma unroll
        for (int r = 0; r < R; ++r) {
            const float xk = xs[r][k], h1k = h1s[r][k], h2k = h2s[r][k];
            const float hs = h1k + h2k;
            ai[r] = fmaf(xk, wi, ai[r]); ai[r] = fmaf(hs, ui, ai[r]);
            ao[r] = fmaf(xk, wo, ao[r]); ao[r] = fmaf(hs, uo, ao[r]);
            au[r] = fmaf(xk, wu, au[r]); au[r] = fmaf(hs, uu, au[r]);
            fx[r] = fmaf(xk, wf, fx[r]);
            g1[r] = fmaf(h1k, uf, g1[r]);
            g2[r] = fmaf(h2k, uf, g2[r]);
        }
    }
    #pragma unroll
    for (int r = 0; r < R; ++r) {
        const float f1 = sigf(fx[r] + g1[r]);
        const float f2 = sigf(fx[r] + g2[r]);
        const float c1 = cbuf[c1base[r] + t];
        const float c2 = cbuf[c2base[r] + t];
        const float c  = sigf(ai[r]) * tanh_fast(au[r]) + f1 * c1 + f2 * c2;
        const float h  = sigf(ao[r]) * tanh_fast(c);
        hbuf[rowbase[r] + t] = f2bf(h);
        cbuf[rowbase[r] + t] = c;
    }
}

__global__ __launch_bounds__(256) void out_kernel(
    const unsigned short* __restrict__ hbuf, const float* __restrict__ cbuf,
    float* __restrict__ out)
{
    const int t = threadIdx.x;
    const int b = blockIdx.x;
    out[b * 512 + t]       = bf2f(hbuf[(b * Nn) * Dd + t]);
    out[b * 512 + 256 + t] = cbuf[(b * Nn) * Dd + t];
}

extern "C" void kernel_launch(void* const* d_in, const int* in_sizes, int n_in,
                              void* d_out, int out_size, void* d_ws, size_t ws_size,
                              hipStream_t stream) {
    const float* x     = (const float*)d_in[0];
    const float* W_iou = (const float*)d_in[1];
    const float* b_iou = (const float*)d_in[2];
    const float* U_iou = (const float*)d_in[3];
    const float* W_f   = (const float*)d_in[4];
    const float* b_f   = (const float*)d_in[5];
    const float* U_f   = (const float*)d_in[6];
    float* out = (float*)d_out;

    const size_t HB = (size_t)Bb * Nn * Dd;                 // 67,106,816
    unsigned short* hbuf = (unsigned short*)d_ws;           // bf16, 134 MB
    float* cbuf = (float*)((char*)d_ws + HB * 2);           // fp32, 268 MB
    unsigned short* Bt  = (unsigned short*)((char*)d_ws + HB * 6);   // 1280x768
    unsigned short* Btl = Bt + 1280 * 768;                  // 768x256

    pack_internal<<<(1280 * 768) / 256, 256, 0, stream>>>(W_iou, U_iou, W_f, U_f, Bt);
    pack_leaf<<<(768 * 256) / 256, 256, 0, stream>>>(W_iou, Btl);

    gemm_leaf<<<dim3((Bb * Lleaf) / 128, 4), 256, 0, stream>>>(x, Btl, b_iou, hbuf, cbuf);

    for (int lvl = 13; lvl >= 4; --lvl) {                   // n = 8192 .. 16
        const int n = 1 << lvl;
        gemm_level<<<dim3((Bb * n) / 128, 8), 256, 0, stream>>>(
            x, Bt, b_iou, b_f, hbuf, cbuf, n, lvl);
    }
    for (int n = 8; n >= 1; n >>= 1) {
        level_small<<<n, 256, 0, stream>>>(
            x, W_iou, b_iou, U_iou, W_f, b_f, U_f, hbuf, cbuf, n);
    }
    out_kernel<<<Bb, 256, 0, stream>>>(hbuf, cbuf, out);
}

// Round 3
// 1418.861 us; speedup vs baseline: 3.0628x; 1.1953x over previous
//
#include <hip/hip_runtime.h>
#include <math.h>

// ChildSumTreeLSTM, round 3: global_load_lds(16B) staging + XOR-swizzled LDS.
// A = [x | h1 | h2] (K=768), Bt = packed weights [1280][768] K-major,
// gate-interleaved cols (col' = 80q+16g+r, g in {i,o,u,f1,f2}) -> fused
// LSTM epilogue. h stored bf16, c fp32. Internal-node x pre-converted to
// bf16 (xbf) so ALL level staging is direct global->LDS DMA.
// LDS layout (per 64-k chunk): slot(row,p) = row*8 + (p ^ (row&7)), p = k/8.
// Wave-uniform-base rule: lane i of row-group g loads row g*8+(i>>3),
// part (i&7)^(i>>3), landing at base+16*i == slot ✓. Frag reads 2-way only.

#define Bb 8
#define Lleaf 16384
#define Nn 32767
#define NInt 16383
#define Dd 256

typedef __attribute__((ext_vector_type(8))) short short8;
typedef __attribute__((ext_vector_type(4))) float float4v;

__device__ __forceinline__ float sigf(float x) {
    return __builtin_amdgcn_rcpf(1.0f + __expf(-x));
}
__device__ __forceinline__ float tanh_fast(float x) {
    return fmaf(2.0f, sigf(2.0f * x), -1.0f);
}
__device__ __forceinline__ unsigned short f2bf(float f) {
    unsigned int u = __float_as_uint(f);
    u = (u + 0x7FFFu + ((u >> 16) & 1u)) >> 16;   // RTNE, finite inputs
    return (unsigned short)u;
}
__device__ __forceinline__ float bf2f(unsigned short h) {
    return __uint_as_float(((unsigned int)h) << 16);
}
__device__ __forceinline__ void load_lds16(const void* g, void* l) {
    __builtin_amdgcn_global_load_lds(
        (const __attribute__((address_space(1))) unsigned int*)g,
        (__attribute__((address_space(3))) unsigned int*)l, 16, 0, 0);
}

// ---------------- x (internal nodes) fp32 -> bf16 --------------------------
__global__ __launch_bounds__(256) void xcast(
    const float* __restrict__ x, unsigned short* __restrict__ xbf)
{
    const int base = (blockIdx.x * 256 + threadIdx.x) * 8;   // < 8*NInt*256
    const int node = base >> 8;               // = b*NInt + g
    const int b = node / NInt, g = node - b * NInt;
    const int off = base & 255;
    const float4* p = (const float4*)(x + (((size_t)(b * Nn + g)) << 8) + off);
    const float4 f0 = p[0], f1 = p[1];
    union { unsigned short us[8]; uint4 v; } pk;
    pk.us[0] = f2bf(f0.x); pk.us[1] = f2bf(f0.y);
    pk.us[2] = f2bf(f0.z); pk.us[3] = f2bf(f0.w);
    pk.us[4] = f2bf(f1.x); pk.us[5] = f2bf(f1.y);
    pk.us[6] = f2bf(f1.z); pk.us[7] = f2bf(f1.w);
    *(uint4*)(xbf + base) = pk.v;
}

// ---------------- weight packing (once per call, ~2 MB) --------------------
__global__ __launch_bounds__(256) void pack_internal(
    const float* __restrict__ W_iou, const float* __restrict__ U_iou,
    const float* __restrict__ W_f,   const float* __restrict__ U_f,
    unsigned short* __restrict__ Bt)
{
    const int idx = blockIdx.x * 256 + threadIdx.x;      // < 1280*768
    const int col = idx / 768, k = idx - col * 768;
    const int q = col / 80, rem = col - q * 80;
    const int g = rem >> 4, r = rem & 15;
    const int d = (q << 4) + r;
    const int seg = k >> 8, kk = k & 255;
    float val;
    if (g < 3) {
        val = (seg == 0) ? W_iou[kk * 768 + g * 256 + d]
                         : U_iou[kk * 768 + g * 256 + d];
    } else if (seg == 0) {
        val = W_f[kk * 256 + d];
    } else if (seg == 1) {
        val = (g == 3) ? U_f[kk * 256 + d] : 0.0f;
    } else {
        val = (g == 4) ? U_f[kk * 256 + d] : 0.0f;
    }
    Bt[idx] = f2bf(val);
}

__global__ __launch_bounds__(256) void pack_leaf(
    const float* __restrict__ W_iou, unsigned short* __restrict__ Btl)
{
    const int idx = blockIdx.x * 256 + threadIdx.x;      // < 768*256
    const int col = idx >> 8, k = idx & 255;
    const int q = col / 48, rem = col - q * 48;
    const int g = rem >> 4, r = rem & 15;
    const int d = (q << 4) + r;
    Btl[idx] = f2bf(W_iou[k * 768 + g * 256 + d]);
}

// ---------------- internal level MFMA GEMM ---------------------------------
// grid (8n/128, 8); tile M=128, N=160, K=768, BK=64, all staging via
// global_load_lds into XOR-swizzled LDS.
__global__ __launch_bounds__(256) void gemm_level(
    const unsigned short* __restrict__ xbf, const unsigned short* __restrict__ Bt,
    const float* __restrict__ b_iou, const float* __restrict__ b_f,
    unsigned short* __restrict__ hbuf, float* __restrict__ cbuf,
    int n, int lvl)
{
    __shared__ unsigned short Alds[128 * 64];   // 16 KB, swizzled
    __shared__ unsigned short Blds[160 * 64];   // 20 KB, swizzled
    const int tid  = threadIdx.x;
    const int wave = tid >> 6, lane = tid & 63;
    const int l16  = lane & 15, q4 = lane >> 4;
    const int m0   = blockIdx.x * 128;
    const int n0   = blockIdx.y * 160;
    const int lr   = lane >> 3;                 // row-in-group 0..7
    const int lp   = (lane & 7) ^ lr;           // swizzled k-part

    float4v acc[2][10];
    #pragma unroll
    for (int qq = 0; qq < 2; ++qq) {
        const int d = ((blockIdx.y * 2 + qq) << 4) + l16;
        float bv0 = b_iou[d], bv1 = b_iou[256 + d], bv2 = b_iou[512 + d];
        float bv3 = b_f[d];
        float bv[5] = {bv0, bv1, bv2, bv3, bv3};
        #pragma unroll
        for (int g = 0; g < 5; ++g) {
            float4v v; v[0] = bv[g]; v[1] = bv[g]; v[2] = bv[g]; v[3] = bv[g];
            acc[0][qq * 5 + g] = v; acc[1][qq * 5 + g] = v;
        }
    }

    for (int kk = 0; kk < 12; ++kk) {          // segs: 0-3 x, 4-7 h1, 8-11 h2
        __syncthreads();
        // stage A: 16 row-groups of 8 rows x 64k
        #pragma unroll
        for (int it = 0; it < 4; ++it) {
            const int g = it * 4 + wave;       // 0..15
            const int r = g * 8 + lr;
            const int m = m0 + r;
            const int b = m >> lvl, j = m & (n - 1);
            const unsigned short* src;
            if (kk < 4) {
                src = xbf + (((b * NInt + n - 1 + j) << 8) + kk * 64 + lp * 8);
            } else {
                const int child = 2 * n - 1 + 2 * j + (kk >= 8 ? 1 : 0);
                src = hbuf + (((b * Nn + child) << 8) + ((kk - 4) & 3) * 64 + lp * 8);
            }
            load_lds16(src, &Alds[g * 512]);
        }
        // stage B: 20 row-groups
        #pragma unroll
        for (int it = 0; it < 5; ++it) {
            const int g = it * 4 + wave;       // 0..19
            const int row = g * 8 + lr;
            load_lds16(Bt + ((n0 + row) * 768 + kk * 64 + lp * 8), &Blds[g * 512]);
        }
        __syncthreads();
        #pragma unroll
        for (int ks = 0; ks < 2; ++ks) {
            const int pa = ks * 4 + q4;
            const int sw = (pa ^ (l16 & 7)) * 8;
            const short8 a0 = *(const short8*)&Alds[(wave * 32 + l16) * 64 + sw];
            const short8 a1 = *(const short8*)&Alds[(wave * 32 + 16 + l16) * 64 + sw];
            #pragma unroll
            for (int ni = 0; ni < 10; ++ni) {
                const short8 bf = *(const short8*)&Blds[(ni * 16 + l16) * 64 + sw];
                acc[0][ni] = __builtin_amdgcn_mfma_f32_16x16x32_bf16(a0, bf, acc[0][ni], 0, 0, 0);
                acc[1][ni] = __builtin_amdgcn_mfma_f32_16x16x32_bf16(a1, bf, acc[1][ni], 0, 0, 0);
            }
        }
    }

    // fused LSTM epilogue: C/D row = q4*4+reg, col = l16
    #pragma unroll
    for (int mi = 0; mi < 2; ++mi) {
        #pragma unroll
        for (int reg = 0; reg < 4; ++reg) {
            const int row_l = wave * 32 + mi * 16 + (q4 << 2) + reg;
            const int m = m0 + row_l;
            const int b = m >> lvl, j = m & (n - 1);
            const int nb = b * Nn;
            const int cbase = (nb + 2 * n - 1 + 2 * j) << 8;
            const int obase = (nb + n - 1 + j) << 8;
            #pragma unroll
            for (int qq = 0; qq < 2; ++qq) {
                const int d = ((blockIdx.y * 2 + qq) << 4) + l16;
                const float i_ = acc[mi][qq * 5 + 0][reg];
                const float o_ = acc[mi][qq * 5 + 1][reg];
                const float u_ = acc[mi][qq * 5 + 2][reg];
                const float f1 = acc[mi][qq * 5 + 3][reg];
                const float f2 = acc[mi][qq * 5 + 4][reg];
                const float c1 = cbuf[cbase + d];
                const float c2 = cbuf[cbase + 256 + d];
                const float c = sigf(i_) * tanh_fast(u_) + sigf(f1) * c1 + sigf(f2) * c2;
                const float h = sigf(o_) * tanh_fast(c);
                cbuf[obase + d] = c;
                hbuf[obase + d] = f2bf(h);
            }
        }
    }
}

// ---------------- leaf MFMA GEMM -------------------------------------------
// grid (131072/128, 4); tile M=128, N=192, K=256, BK=64.
// A staged via VGPR f2bf into swizzled layout; B via global_load_lds.
__global__ __launch_bounds__(256) void gemm_leaf(
    const float* __restrict__ x, const unsigned short* __restrict__ Btl,
    const float* __restrict__ b_iou,
    unsigned short* __restrict__ hbuf, float* __restrict__ cbuf)
{
    __shared__ unsigned short Alds[128 * 64];   // 16 KB
    __shared__ unsigned short Blds[192 * 64];   // 24 KB
    const int tid  = threadIdx.x;
    const int wave = tid >> 6, lane = tid & 63;
    const int l16  = lane & 15, q4 = lane >> 4;
    const int m0   = blockIdx.x * 128;
    const int n0   = blockIdx.y * 192;
    const int lr   = lane >> 3;
    const int lp   = (lane & 7) ^ lr;

    float4v acc[2][12];
    #pragma unroll
    for (int qq = 0; qq < 4; ++qq) {
        const int d = ((blockIdx.y * 4 + qq) << 4) + l16;
        float bv[3] = {b_iou[d], b_iou[256 + d], b_iou[512 + d]};
        #pragma unroll
        for (int g = 0; g < 3; ++g) {
            float4v v; v[0] = bv[g]; v[1] = bv[g]; v[2] = bv[g]; v[3] = bv[g];
            acc[0][qq * 3 + g] = v; acc[1][qq * 3 + g] = v;
        }
    }

    for (int kk = 0; kk < 4; ++kk) {
        __syncthreads();
        {   // stage A (x fp32 -> bf16, swizzled ds_write_b128: 2-way only)
            int task = tid;
            #pragma unroll
            for (int it = 0; it < 4; ++it, task += 256) {
                const int r = task >> 3, k8 = task & 7;
                const int m = m0 + r;
                const int b = m >> 14, j = m & (Lleaf - 1);
                const int node = b * Nn + (Lleaf - 1) + j;
                const float4* p = (const float4*)(x + ((node << 8) + kk * 64 + (k8 << 3)));
                const float4 f0 = p[0], f1 = p[1];
                union { unsigned short us[8]; uint4 v; } pk;
                pk.us[0] = f2bf(f0.x); pk.us[1] = f2bf(f0.y);
                pk.us[2] = f2bf(f0.z); pk.us[3] = f2bf(f0.w);
                pk.us[4] = f2bf(f1.x); pk.us[5] = f2bf(f1.y);
                pk.us[6] = f2bf(f1.z); pk.us[7] = f2bf(f1.w);
                *(uint4*)&Alds[(r * 8 + (k8 ^ (r & 7))) * 8] = pk.v;
            }
        }
        // stage B: 24 row-groups
        #pragma unroll
        for (int it = 0; it < 6; ++it) {
            const int g = it * 4 + wave;        // 0..23
            const int row = g * 8 + lr;
            load_lds16(Btl + ((n0 + row) * 256 + kk * 64 + lp * 8), &Blds[g * 512]);
        }
        __syncthreads();
        #pragma unroll
        for (int ks = 0; ks < 2; ++ks) {
            const int pa = ks * 4 + q4;
            const int sw = (pa ^ (l16 & 7)) * 8;
            const short8 a0 = *(const short8*)&Alds[(wave * 32 + l16) * 64 + sw];
            const short8 a1 = *(const short8*)&Alds[(wave * 32 + 16 + l16) * 64 + sw];
            #pragma unroll
            for (int ni = 0; ni < 12; ++ni) {
                const short8 bf = *(const short8*)&Blds[(ni * 16 + l16) * 64 + sw];
                acc[0][ni] = __builtin_amdgcn_mfma_f32_16x16x32_bf16(a0, bf, acc[0][ni], 0, 0, 0);
                acc[1][ni] = __builtin_amdgcn_mfma_f32_16x16x32_bf16(a1, bf, acc[1][ni], 0, 0, 0);
            }
        }
    }

    #pragma unroll
    for (int mi = 0; mi < 2; ++mi) {
        #pragma unroll
        for (int reg = 0; reg < 4; ++reg) {
            const int row_l = wave * 32 + mi * 16 + (q4 << 2) + reg;
            const int m = m0 + row_l;
            const int b = m >> 14, j = m & (Lleaf - 1);
            const int obase = (b * Nn + (Lleaf - 1) + j) << 8;
            #pragma unroll
            for (int qq = 0; qq < 4; ++qq) {
                const int d = ((blockIdx.y * 4 + qq) << 4) + l16;
                const float i_ = acc[mi][qq * 3 + 0][reg];
                const float o_ = acc[mi][qq * 3 + 1][reg];
                const float u_ = acc[mi][qq * 3 + 2][reg];
                const float c = sigf(i_) * tanh_fast(u_);
                const float h = sigf(o_) * tanh_fast(c);
                cbuf[obase + d] = c;
                hbuf[obase + d] = f2bf(h);
            }
        }
    }
}

// ---------------- small levels (n<=8): fp32 fallback -----------------------
__global__ __launch_bounds__(256) void level_small(
    const float* __restrict__ x,
    const float* __restrict__ W_iou, const float* __restrict__ b_iou,
    const float* __restrict__ U_iou,
    const float* __restrict__ W_f,   const float* __restrict__ b_f,
    const float* __restrict__ U_f,
    unsigned short* __restrict__ hbuf, float* __restrict__ cbuf, int n)
{
    const int R = 8;
    __shared__ float xs[R][Dd], h1s[R][Dd], h2s[R][Dd];
    const int t = threadIdx.x;

    int rowbase[R], c1base[R], c2base[R];
    #pragma unroll
    for (int r = 0; r < R; ++r) {
        const int m = blockIdx.x * R + r;
        const int b = m / n, j = m % n;
        const int g = n - 1 + j;
        const int nb = b * Nn;
        rowbase[r] = (nb + g) * Dd;
        c1base[r]  = (nb + 2 * g + 1) * Dd;
        c2base[r]  = (nb + 2 * g + 2) * Dd;
        xs[r][t]  = x[rowbase[r] + t];
        h1s[r][t] = bf2f(hbuf[c1base[r] + t]);
        h2s[r][t] = bf2f(hbuf[c2base[r] + t]);
    }
    __syncthreads();

    float ai[R], ao[R], au[R], fx[R], g1[R], g2[R];
    {
        const float bi = b_iou[t], bo = b_iou[256 + t], bu = b_iou[512 + t];
        const float bf = b_f[t];
        #pragma unroll
        for (int r = 0; r < R; ++r) {
            ai[r] = bi; ao[r] = bo; au[r] = bu;
            fx[r] = bf; g1[r] = 0.f; g2[r] = 0.f;
        }
    }
    for (int k = 0; k < Dd; ++k) {
        const float wi = W_iou[k * 768 + t];
        const float wo = W_iou[k * 768 + 256 + t];
        const float wu = W_iou[k * 768 + 512 + t];
        const float ui = U_iou[k * 768 + t];
        const float uo = U_iou[k * 768 + 256 + t];
        const float uu = U_iou[k * 768 + 512 + t];
        const float wf = W_f[k * 256 + t];
        const float uf = U_f[k * 256 + t];
        #pragma unroll
        for (int r = 0; r < R; ++r) {
            const float xk = xs[r][k], h1k = h1s[r][k], h2k = h2s[r][k];
            const float hs = h1k + h2k;
            ai[r] = fmaf(xk, wi, ai[r]); ai[r] = fmaf(hs, ui, ai[r]);
            ao[r] = fmaf(xk, wo, ao[r]); ao[r] = fmaf(hs, uo, ao[r]);
            au[r] = fmaf(xk, wu, au[r]); au[r] = fmaf(hs, uu, au[r]);
            fx[r] = fmaf(xk, wf, fx[r]);
            g1[r] = fmaf(h1k, uf, g1[r]);
            g2[r] = fmaf(h2k, uf, g2[r]);
        }
    }
    #pragma unroll
    for (int r = 0; r < R; ++r) {
        const float f1 = sigf(fx[r] + g1[r]);
        const float f2 = sigf(fx[r] + g2[r]);
        const float c1 = cbuf[c1base[r] + t];
        const float c2 = cbuf[c2base[r] + t];
        const float c  = sigf(ai[r]) * tanh_fast(au[r]) + f1 * c1 + f2 * c2;
        const float h  = sigf(ao[r]) * tanh_fast(c);
        hbuf[rowbase[r] + t] = f2bf(h);
        cbuf[rowbase[r] + t] = c;
    }
}

__global__ __launch_bounds__(256) void out_kernel(
    const unsigned short* __restrict__ hbuf, const float* __restrict__ cbuf,
    float* __restrict__ out)
{
    const int t = threadIdx.x;
    const int b = blockIdx.x;
    out[b * 512 + t]       = bf2f(hbuf[(b * Nn) * Dd + t]);
    out[b * 512 + 256 + t] = cbuf[(b * Nn) * Dd + t];
}

extern "C" void kernel_launch(void* const* d_in, const int* in_sizes, int n_in,
                              void* d_out, int out_size, void* d_ws, size_t ws_size,
                              hipStream_t stream) {
    const float* x     = (const float*)d_in[0];
    const float* W_iou = (const float*)d_in[1];
    const float* b_iou = (const float*)d_in[2];
    const float* U_iou = (const float*)d_in[3];
    const float* W_f   = (const float*)d_in[4];
    const float* b_f   = (const float*)d_in[5];
    const float* U_f   = (const float*)d_in[6];
    float* out = (float*)d_out;

    const size_t HB = (size_t)Bb * Nn * Dd;                 // 67,106,816 elems
    unsigned short* hbuf = (unsigned short*)d_ws;           // bf16, 134 MB
    float* cbuf = (float*)((char*)d_ws + HB * 2);           // fp32, 268 MB
    unsigned short* xbf = (unsigned short*)((char*)d_ws + HB * 6);   // internal x, 67 MB
    unsigned short* Bt  = xbf + (size_t)Bb * NInt * Dd;     // 1280x768
    unsigned short* Btl = Bt + 1280 * 768;                  // 768x256

    xcast<<<NInt, 256, 0, stream>>>(x, xbf);
    pack_internal<<<(1280 * 768) / 256, 256, 0, stream>>>(W_iou, U_iou, W_f, U_f, Bt);
    pack_leaf<<<(768 * 256) / 256, 256, 0, stream>>>(W_iou, Btl);

    gemm_leaf<<<dim3((Bb * Lleaf) / 128, 4), 256, 0, stream>>>(x, Btl, b_iou, hbuf, cbuf);

    for (int lvl = 13; lvl >= 4; --lvl) {                   // n = 8192 .. 16
        const int n = 1 << lvl;
        gemm_level<<<dim3((Bb * n) / 128, 8), 256, 0, stream>>>(
            xbf, Bt, b_iou, b_f, hbuf, cbuf, n, lvl);
    }
    for (int n = 8; n >= 1; n >>= 1) {
        level_small<<<n, 256, 0, stream>>>(
            x, W_iou, b_iou, U_iou, W_f, b_f, U_f, hbuf, cbuf, n);
    }
    out_kernel<<<Bb, 256, 0, stream>>>(hbuf, cbuf, out);
}

// Round 4
// 1049.944 us; speedup vs baseline: 4.1390x; 1.3514x over previous
//
#include <hip/hip_runtime.h>
#include <math.h>

// ChildSumTreeLSTM, round 4.
// - gemm_level_big (lvl>=7): uniform batch per tile -> SGPR bases,
//   __launch_bounds__(256,3) to cross the 3-wave/SIMD reg cliff (was 172 regs).
// - gemm_level (generic) for lvl 6..4.
// - gemm_small (M=64 MFMA, clamped loads/guarded stores) for lvl 3..0,
//   replacing the fp32 weight-streaming level_small.
// - leaf: N-tile 96 (acc 48 AGPRs, was 96), 3 waves/SIMD.
// Layout as round 3: Bt [1280][768] K-major, gate-interleaved cols
// (col' = 80q+16g+r, g in {i,o,u,f1,f2}); XOR-swizzled LDS; h bf16, c fp32.

#define Bb 8
#define Lleaf 16384
#define Nn 32767
#define NInt 16383
#define Dd 256

typedef __attribute__((ext_vector_type(8))) short short8;
typedef __attribute__((ext_vector_type(4))) float float4v;

__device__ __forceinline__ float sigf(float x) {
    return __builtin_amdgcn_rcpf(1.0f + __expf(-x));
}
__device__ __forceinline__ float tanh_fast(float x) {
    return fmaf(2.0f, sigf(2.0f * x), -1.0f);
}
__device__ __forceinline__ unsigned short f2bf(float f) {
    unsigned int u = __float_as_uint(f);
    u = (u + 0x7FFFu + ((u >> 16) & 1u)) >> 16;   // RTNE, finite inputs
    return (unsigned short)u;
}
__device__ __forceinline__ float bf2f(unsigned short h) {
    return __uint_as_float(((unsigned int)h) << 16);
}
__device__ __forceinline__ void load_lds16(const void* g, void* l) {
    __builtin_amdgcn_global_load_lds(
        (const __attribute__((address_space(1))) unsigned int*)g,
        (__attribute__((address_space(3))) unsigned int*)l, 16, 0, 0);
}

// ---------------- x (internal nodes) fp32 -> bf16 --------------------------
__global__ __launch_bounds__(256) void xcast(
    const float* __restrict__ x, unsigned short* __restrict__ xbf)
{
    const int base = (blockIdx.x * 256 + threadIdx.x) * 8;   // < 8*NInt*256
    const int node = base >> 8;               // = b*NInt + g
    const int b = node / NInt, g = node - b * NInt;
    const int off = base & 255;
    const float4* p = (const float4*)(x + (((size_t)(b * Nn + g)) << 8) + off);
    const float4 f0 = p[0], f1 = p[1];
    union { unsigned short us[8]; uint4 v; } pk;
    pk.us[0] = f2bf(f0.x); pk.us[1] = f2bf(f0.y);
    pk.us[2] = f2bf(f0.z); pk.us[3] = f2bf(f0.w);
    pk.us[4] = f2bf(f1.x); pk.us[5] = f2bf(f1.y);
    pk.us[6] = f2bf(f1.z); pk.us[7] = f2bf(f1.w);
    *(uint4*)(xbf + base) = pk.v;
}

// ---------------- weight packing (once per call, ~2 MB) --------------------
__global__ __launch_bounds__(256) void pack_internal(
    const float* __restrict__ W_iou, const float* __restrict__ U_iou,
    const float* __restrict__ W_f,   const float* __restrict__ U_f,
    unsigned short* __restrict__ Bt)
{
    const int idx = blockIdx.x * 256 + threadIdx.x;      // < 1280*768
    const int col = idx / 768, k = idx - col * 768;
    const int q = col / 80, rem = col - q * 80;
    const int g = rem >> 4, r = rem & 15;
    const int d = (q << 4) + r;
    const int seg = k >> 8, kk = k & 255;
    float val;
    if (g < 3) {
        val = (seg == 0) ? W_iou[kk * 768 + g * 256 + d]
                         : U_iou[kk * 768 + g * 256 + d];
    } else if (seg == 0) {
        val = W_f[kk * 256 + d];
    } else if (seg == 1) {
        val = (g == 3) ? U_f[kk * 256 + d] : 0.0f;
    } else {
        val = (g == 4) ? U_f[kk * 256 + d] : 0.0f;
    }
    Bt[idx] = f2bf(val);
}

__global__ __launch_bounds__(256) void pack_leaf(
    const float* __restrict__ W_iou, unsigned short* __restrict__ Btl)
{
    const int idx = blockIdx.x * 256 + threadIdx.x;      // < 768*256
    const int col = idx >> 8, k = idx & 255;
    const int q = col / 48, rem = col - q * 48;
    const int g = rem >> 4, r = rem & 15;
    const int d = (q << 4) + r;
    Btl[idx] = f2bf(W_iou[k * 768 + g * 256 + d]);
}

// ---------------- big internal levels (n >= 128): uniform batch ------------
__global__ __launch_bounds__(256, 3) void gemm_level_big(
    const unsigned short* __restrict__ xbf, const unsigned short* __restrict__ Bt,
    const float* __restrict__ b_iou, const float* __restrict__ b_f,
    unsigned short* __restrict__ hbuf, float* __restrict__ cbuf,
    int n, int lvl)
{
    __shared__ unsigned short Alds[128 * 64];   // 16 KB, swizzled
    __shared__ unsigned short Blds[160 * 64];   // 20 KB, swizzled
    const int tid  = threadIdx.x;
    const int wave = tid >> 6, lane = tid & 63;
    const int l16  = lane & 15, q4 = lane >> 4;
    const int m0   = blockIdx.x * 128;
    const int n0   = blockIdx.y * 160;
    const int lr   = lane >> 3;                 // row-in-group 0..7
    const int lp   = (lane & 7) ^ lr;           // swizzled k-part

    // whole tile lives in one batch (n >= 128, m0 multiple of 128)
    const int b  = m0 >> lvl;
    const int j0 = m0 & (n - 1);
    const int xb0 = b * NInt + n - 1 + j0;      // xbf node base  (+r)
    const int cb0 = b * Nn + 2 * n - 1 + 2 * j0;// child node base (+2r+sel)
    const int ob0 = b * Nn + n - 1 + j0;        // output node base (+r)

    float4v acc[2][10];
    #pragma unroll
    for (int qq = 0; qq < 2; ++qq) {
        const int d = ((blockIdx.y * 2 + qq) << 4) + l16;
        float bv0 = b_iou[d], bv1 = b_iou[256 + d], bv2 = b_iou[512 + d];
        float bv3 = b_f[d];
        float bv[5] = {bv0, bv1, bv2, bv3, bv3};
        #pragma unroll
        for (int g = 0; g < 5; ++g) {
            float4v v; v[0] = bv[g]; v[1] = bv[g]; v[2] = bv[g]; v[3] = bv[g];
            acc[0][qq * 5 + g] = v; acc[1][qq * 5 + g] = v;
        }
    }

    for (int kk = 0; kk < 12; ++kk) {          // segs: 0-3 x, 4-7 h1, 8-11 h2
        __syncthreads();
        #pragma unroll
        for (int it = 0; it < 4; ++it) {        // stage A
            const int g = it * 4 + wave;       // 0..15
            const int r = g * 8 + lr;
            const unsigned short* src;
            if (kk < 4) {
                src = xbf + (((xb0 + r) << 8) + kk * 64 + lp * 8);
            } else {
                const int sel = (kk >= 8) ? 1 : 0;
                src = hbuf + (((cb0 + 2 * r + sel) << 8) + ((kk - 4) & 3) * 64 + lp * 8);
            }
            load_lds16(src, &Alds[g * 512]);
        }
        #pragma unroll
        for (int it = 0; it < 5; ++it) {        // stage B
            const int g = it * 4 + wave;       // 0..19
            const int row = g * 8 + lr;
            load_lds16(Bt + ((n0 + row) * 768 + kk * 64 + lp * 8), &Blds[g * 512]);
        }
        __syncthreads();
        #pragma unroll
        for (int ks = 0; ks < 2; ++ks) {
            const int pa = ks * 4 + q4;
            const int sw = (pa ^ (l16 & 7)) * 8;
            const short8 a0 = *(const short8*)&Alds[(wave * 32 + l16) * 64 + sw];
            const short8 a1 = *(const short8*)&Alds[(wave * 32 + 16 + l16) * 64 + sw];
            #pragma unroll
            for (int ni = 0; ni < 10; ++ni) {
                const short8 bf = *(const short8*)&Blds[(ni * 16 + l16) * 64 + sw];
                acc[0][ni] = __builtin_amdgcn_mfma_f32_16x16x32_bf16(a0, bf, acc[0][ni], 0, 0, 0);
                acc[1][ni] = __builtin_amdgcn_mfma_f32_16x16x32_bf16(a1, bf, acc[1][ni], 0, 0, 0);
            }
        }
    }

    #pragma unroll
    for (int mi = 0; mi < 2; ++mi) {
        #pragma unroll
        for (int reg = 0; reg < 4; ++reg) {
            const int row_l = wave * 32 + mi * 16 + (q4 << 2) + reg;
            const int cbase = (cb0 + 2 * row_l) << 8;
            const int obase = (ob0 + row_l) << 8;
            #pragma unroll
            for (int qq = 0; qq < 2; ++qq) {
                const int d = ((blockIdx.y * 2 + qq) << 4) + l16;
                const float i_ = acc[mi][qq * 5 + 0][reg];
                const float o_ = acc[mi][qq * 5 + 1][reg];
                const float u_ = acc[mi][qq * 5 + 2][reg];
                const float f1 = acc[mi][qq * 5 + 3][reg];
                const float f2 = acc[mi][qq * 5 + 4][reg];
                const float c1 = cbuf[cbase + d];
                const float c2 = cbuf[cbase + 256 + d];
                const float c = sigf(i_) * tanh_fast(u_) + sigf(f1) * c1 + sigf(f2) * c2;
                const float h = sigf(o_) * tanh_fast(c);
                cbuf[obase + d] = c;
                hbuf[obase + d] = f2bf(h);
            }
        }
    }
}

// ---------------- generic internal level (lvl 6..4) ------------------------
__global__ __launch_bounds__(256) void gemm_level(
    const unsigned short* __restrict__ xbf, const unsigned short* __restrict__ Bt,
    const float* __restrict__ b_iou, const float* __restrict__ b_f,
    unsigned short* __restrict__ hbuf, float* __restrict__ cbuf,
    int n, int lvl)
{
    __shared__ unsigned short Alds[128 * 64];
    __shared__ unsigned short Blds[160 * 64];
    const int tid  = threadIdx.x;
    const int wave = tid >> 6, lane = tid & 63;
    const int l16  = lane & 15, q4 = lane >> 4;
    const int m0   = blockIdx.x * 128;
    const int n0   = blockIdx.y * 160;
    const int lr   = lane >> 3;
    const int lp   = (lane & 7) ^ lr;

    float4v acc[2][10];
    #pragma unroll
    for (int qq = 0; qq < 2; ++qq) {
        const int d = ((blockIdx.y * 2 + qq) << 4) + l16;
        float bv0 = b_iou[d], bv1 = b_iou[256 + d], bv2 = b_iou[512 + d];
        float bv3 = b_f[d];
        float bv[5] = {bv0, bv1, bv2, bv3, bv3};
        #pragma unroll
        for (int g = 0; g < 5; ++g) {
            float4v v; v[0] = bv[g]; v[1] = bv[g]; v[2] = bv[g]; v[3] = bv[g];
            acc[0][qq * 5 + g] = v; acc[1][qq * 5 + g] = v;
        }
    }

    for (int kk = 0; kk < 12; ++kk) {
        __syncthreads();
        #pragma unroll
        for (int it = 0; it < 4; ++it) {
            const int g = it * 4 + wave;
            const int r = g * 8 + lr;
            const int m = m0 + r;
            const int b = m >> lvl, j = m & (n - 1);
            const unsigned short* src;
            if (kk < 4) {
                src = xbf + (((b * NInt + n - 1 + j) << 8) + kk * 64 + lp * 8);
            } else {
                const int child = 2 * n - 1 + 2 * j + (kk >= 8 ? 1 : 0);
                src = hbuf + (((b * Nn + child) << 8) + ((kk - 4) & 3) * 64 + lp * 8);
            }
            load_lds16(src, &Alds[g * 512]);
        }
        #pragma unroll
        for (int it = 0; it < 5; ++it) {
            const int g = it * 4 + wave;
            const int row = g * 8 + lr;
            load_lds16(Bt + ((n0 + row) * 768 + kk * 64 + lp * 8), &Blds[g * 512]);
        }
        __syncthreads();
        #pragma unroll
        for (int ks = 0; ks < 2; ++ks) {
            const int pa = ks * 4 + q4;
            const int sw = (pa ^ (l16 & 7)) * 8;
            const short8 a0 = *(const short8*)&Alds[(wave * 32 + l16) * 64 + sw];
            const short8 a1 = *(const short8*)&Alds[(wave * 32 + 16 + l16) * 64 + sw];
            #pragma unroll
            for (int ni = 0; ni < 10; ++ni) {
                const short8 bf = *(const short8*)&Blds[(ni * 16 + l16) * 64 + sw];
                acc[0][ni] = __builtin_amdgcn_mfma_f32_16x16x32_bf16(a0, bf, acc[0][ni], 0, 0, 0);
                acc[1][ni] = __builtin_amdgcn_mfma_f32_16x16x32_bf16(a1, bf, acc[1][ni], 0, 0, 0);
            }
        }
    }

    #pragma unroll
    for (int mi = 0; mi < 2; ++mi) {
        #pragma unroll
        for (int reg = 0; reg < 4; ++reg) {
            const int row_l = wave * 32 + mi * 16 + (q4 << 2) + reg;
            const int m = m0 + row_l;
            const int b = m >> lvl, j = m & (n - 1);
            const int nb = b * Nn;
            const int cbase = (nb + 2 * n - 1 + 2 * j) << 8;
            const int obase = (nb + n - 1 + j) << 8;
            #pragma unroll
            for (int qq = 0; qq < 2; ++qq) {
                const int d = ((blockIdx.y * 2 + qq) << 4) + l16;
                const float i_ = acc[mi][qq * 5 + 0][reg];
                const float o_ = acc[mi][qq * 5 + 1][reg];
                const float u_ = acc[mi][qq * 5 + 2][reg];
                const float f1 = acc[mi][qq * 5 + 3][reg];
                const float f2 = acc[mi][qq * 5 + 4][reg];
                const float c1 = cbuf[cbase + d];
                const float c2 = cbuf[cbase + 256 + d];
                const float c = sigf(i_) * tanh_fast(u_) + sigf(f1) * c1 + sigf(f2) * c2;
                const float h = sigf(o_) * tanh_fast(c);
                cbuf[obase + d] = c;
                hbuf[obase + d] = f2bf(h);
            }
        }
    }
}

// ---------------- tiny levels (n <= 8): M=64 MFMA, clamp+guard -------------
__global__ __launch_bounds__(256) void gemm_small(
    const unsigned short* __restrict__ xbf, const unsigned short* __restrict__ Bt,
    const float* __restrict__ b_iou, const float* __restrict__ b_f,
    unsigned short* __restrict__ hbuf, float* __restrict__ cbuf,
    int n, int lvl)
{
    __shared__ unsigned short Alds[64 * 64];    // 8 KB
    __shared__ unsigned short Blds[160 * 64];   // 20 KB
    const int tid  = threadIdx.x;
    const int wave = tid >> 6, lane = tid & 63;
    const int l16  = lane & 15, q4 = lane >> 4;
    const int n0   = blockIdx.y * 160;
    const int lr   = lane >> 3;
    const int lp   = (lane & 7) ^ lr;
    const int rmax = 8 * n - 1;

    float4v acc[10];
    #pragma unroll
    for (int qq = 0; qq < 2; ++qq) {
        const int d = ((blockIdx.y * 2 + qq) << 4) + l16;
        float bv0 = b_iou[d], bv1 = b_iou[256 + d], bv2 = b_iou[512 + d];
        float bv3 = b_f[d];
        float bv[5] = {bv0, bv1, bv2, bv3, bv3};
        #pragma unroll
        for (int g = 0; g < 5; ++g) {
            float4v v; v[0] = bv[g]; v[1] = bv[g]; v[2] = bv[g]; v[3] = bv[g];
            acc[qq * 5 + g] = v;
        }
    }

    for (int kk = 0; kk < 12; ++kk) {
        __syncthreads();
        #pragma unroll
        for (int it = 0; it < 2; ++it) {        // stage A: 8 row-groups
            const int g = it * 4 + wave;       // 0..7
            const int r = g * 8 + lr;
            const int m = (r > rmax) ? rmax : r;
            const int b = m >> lvl, j = m & (n - 1);
            const unsigned short* src;
            if (kk < 4) {
                src = xbf + (((b * NInt + n - 1 + j) << 8) + kk * 64 + lp * 8);
            } else {
                const int child = 2 * n - 1 + 2 * j + (kk >= 8 ? 1 : 0);
                src = hbuf + (((b * Nn + child) << 8) + ((kk - 4) & 3) * 64 + lp * 8);
            }
            load_lds16(src, &Alds[g * 512]);
        }
        #pragma unroll
        for (int it = 0; it < 5; ++it) {        // stage B
            const int g = it * 4 + wave;
            const int row = g * 8 + lr;
            load_lds16(Bt + ((n0 + row) * 768 + kk * 64 + lp * 8), &Blds[g * 512]);
        }
        __syncthreads();
        #pragma unroll
        for (int ks = 0; ks < 2; ++ks) {
            const int pa = ks * 4 + q4;
            const int sw = (pa ^ (l16 & 7)) * 8;
            const short8 a0 = *(const short8*)&Alds[(wave * 16 + l16) * 64 + sw];
            #pragma unroll
            for (int ni = 0; ni < 10; ++ni) {
                const short8 bf = *(const short8*)&Blds[(ni * 16 + l16) * 64 + sw];
                acc[ni] = __builtin_amdgcn_mfma_f32_16x16x32_bf16(a0, bf, acc[ni], 0, 0, 0);
            }
        }
    }

    #pragma unroll
    for (int reg = 0; reg < 4; ++reg) {
        const int row_l = wave * 16 + (q4 << 2) + reg;
        const int m = (row_l > rmax) ? rmax : row_l;
        const bool valid = (row_l <= rmax);
        const int b = m >> lvl, j = m & (n - 1);
        const int nb = b * Nn;
        const int cbase = (nb + 2 * n - 1 + 2 * j) << 8;
        const int obase = (nb + n - 1 + j) << 8;
        #pragma unroll
        for (int qq = 0; qq < 2; ++qq) {
            const int d = ((blockIdx.y * 2 + qq) << 4) + l16;
            const float i_ = acc[qq * 5 + 0][reg];
            const float o_ = acc[qq * 5 + 1][reg];
            const float u_ = acc[qq * 5 + 2][reg];
            const float f1 = acc[qq * 5 + 3][reg];
            const float f2 = acc[qq * 5 + 4][reg];
            const float c1 = cbuf[cbase + d];
            const float c2 = cbuf[cbase + 256 + d];
            const float c = sigf(i_) * tanh_fast(u_) + sigf(f1) * c1 + sigf(f2) * c2;
            const float h = sigf(o_) * tanh_fast(c);
            if (valid) {
                cbuf[obase + d] = c;
                hbuf[obase + d] = f2bf(h);
            }
        }
    }
}

// ---------------- leaf MFMA GEMM -------------------------------------------
// grid (131072/128, 8); tile M=128, N=96 (2 q-groups of 48), K=256, BK=64.
__global__ __launch_bounds__(256, 3) void gemm_leaf(
    const float* __restrict__ x, const unsigned short* __restrict__ Btl,
    const float* __restrict__ b_iou,
    unsigned short* __restrict__ hbuf, float* __restrict__ cbuf)
{
    __shared__ unsigned short Alds[128 * 64];   // 16 KB
    __shared__ unsigned short Blds[96 * 64];    // 12 KB
    const int tid  = threadIdx.x;
    const int wave = tid >> 6, lane = tid & 63;
    const int l16  = lane & 15, q4 = lane >> 4;
    const int m0   = blockIdx.x * 128;
    const int n0   = blockIdx.y * 96;
    const int lr   = lane >> 3;
    const int lp   = (lane & 7) ^ lr;

    // tile fully within one batch (m0 multiple of 128, L multiple of 128)
    const int b   = m0 >> 14;
    const int j0  = m0 & (Lleaf - 1);
    const int nb0 = b * Nn + (Lleaf - 1) + j0;

    float4v acc[2][6];
    #pragma unroll
    for (int qq = 0; qq < 2; ++qq) {
        const int d = ((blockIdx.y * 2 + qq) << 4) + l16;
        float bv[3] = {b_iou[d], b_iou[256 + d], b_iou[512 + d]};
        #pragma unroll
        for (int g = 0; g < 3; ++g) {
            float4v v; v[0] = bv[g]; v[1] = bv[g]; v[2] = bv[g]; v[3] = bv[g];
            acc[0][qq * 3 + g] = v; acc[1][qq * 3 + g] = v;
        }
    }

    for (int kk = 0; kk < 4; ++kk) {
        __syncthreads();
        {   // stage A (x fp32 -> bf16, swizzled ds_write_b128: 2-way only)
            int task = tid;
            #pragma unroll
            for (int it = 0; it < 4; ++it, task += 256) {
                const int r = task >> 3, k8 = task & 7;
                const float4* p = (const float4*)(x +
                    (((nb0 + r) << 8) + kk * 64 + (k8 << 3)));
                const float4 f0 = p[0], f1 = p[1];
                union { unsigned short us[8]; uint4 v; } pk;
                pk.us[0] = f2bf(f0.x); pk.us[1] = f2bf(f0.y);
                pk.us[2] = f2bf(f0.z); pk.us[3] = f2bf(f0.w);
                pk.us[4] = f2bf(f1.x); pk.us[5] = f2bf(f1.y);
                pk.us[6] = f2bf(f1.z); pk.us[7] = f2bf(f1.w);
                *(uint4*)&Alds[(r * 8 + (k8 ^ (r & 7))) * 8] = pk.v;
            }
        }
        // stage B: 12 row-groups
        #pragma unroll
        for (int it = 0; it < 3; ++it) {
            const int g = it * 4 + wave;        // 0..11
            const int row = g * 8 + lr;
            load_lds16(Btl + ((n0 + row) * 256 + kk * 64 + lp * 8), &Blds[g * 512]);
        }
        __syncthreads();
        #pragma unroll
        for (int ks = 0; ks < 2; ++ks) {
            const int pa = ks * 4 + q4;
            const int sw = (pa ^ (l16 & 7)) * 8;
            const short8 a0 = *(const short8*)&Alds[(wave * 32 + l16) * 64 + sw];
            const short8 a1 = *(const short8*)&Alds[(wave * 32 + 16 + l16) * 64 + sw];
            #pragma unroll
            for (int ni = 0; ni < 6; ++ni) {
                const short8 bf = *(const short8*)&Blds[(ni * 16 + l16) * 64 + sw];
                acc[0][ni] = __builtin_amdgcn_mfma_f32_16x16x32_bf16(a0, bf, acc[0][ni], 0, 0, 0);
                acc[1][ni] = __builtin_amdgcn_mfma_f32_16x16x32_bf16(a1, bf, acc[1][ni], 0, 0, 0);
            }
        }
    }

    #pragma unroll
    for (int mi = 0; mi < 2; ++mi) {
        #pragma unroll
        for (int reg = 0; reg < 4; ++reg) {
            const int row_l = wave * 32 + mi * 16 + (q4 << 2) + reg;
            const int obase = (nb0 + row_l) << 8;
            #pragma unroll
            for (int qq = 0; qq < 2; ++qq) {
                const int d = ((blockIdx.y * 2 + qq) << 4) + l16;
                const float i_ = acc[mi][qq * 3 + 0][reg];
                const float o_ = acc[mi][qq * 3 + 1][reg];
                const float u_ = acc[mi][qq * 3 + 2][reg];
                const float c = sigf(i_) * tanh_fast(u_);
                const float h = sigf(o_) * tanh_fast(c);
                cbuf[obase + d] = c;
                hbuf[obase + d] = f2bf(h);
            }
        }
    }
}

__global__ __launch_bounds__(256) void out_kernel(
    const unsigned short* __restrict__ hbuf, const float* __restrict__ cbuf,
    float* __restrict__ out)
{
    const int t = threadIdx.x;
    const int b = blockIdx.x;
    out[b * 512 + t]       = bf2f(hbuf[(b * Nn) * Dd + t]);
    out[b * 512 + 256 + t] = cbuf[(b * Nn) * Dd + t];
}

extern "C" void kernel_launch(void* const* d_in, const int* in_sizes, int n_in,
                              void* d_out, int out_size, void* d_ws, size_t ws_size,
                              hipStream_t stream) {
    const float* x     = (const float*)d_in[0];
    const float* W_iou = (const float*)d_in[1];
    const float* b_iou = (const float*)d_in[2];
    const float* U_iou = (const float*)d_in[3];
    const float* W_f   = (const float*)d_in[4];
    const float* b_f   = (const float*)d_in[5];
    const float* U_f   = (const float*)d_in[6];
    float* out = (float*)d_out;

    const size_t HB = (size_t)Bb * Nn * Dd;                 // 67,106,816 elems
    unsigned short* hbuf = (unsigned short*)d_ws;           // bf16, 134 MB
    float* cbuf = (float*)((char*)d_ws + HB * 2);           // fp32, 268 MB
    unsigned short* xbf = (unsigned short*)((char*)d_ws + HB * 6);   // internal x, 67 MB
    unsigned short* Bt  = xbf + (size_t)Bb * NInt * Dd;     // 1280x768
    unsigned short* Btl = Bt + 1280 * 768;                  // 768x256

    xcast<<<NInt, 256, 0, stream>>>(x, xbf);
    pack_internal<<<(1280 * 768) / 256, 256, 0, stream>>>(W_iou, U_iou, W_f, U_f, Bt);
    pack_leaf<<<(768 * 256) / 256, 256, 0, stream>>>(W_iou, Btl);

    gemm_leaf<<<dim3((Bb * Lleaf) / 128, 8), 256, 0, stream>>>(x, Btl, b_iou, hbuf, cbuf);

    for (int lvl = 13; lvl >= 7; --lvl) {                   // n = 8192 .. 128
        const int n = 1 << lvl;
        gemm_level_big<<<dim3((Bb * n) / 128, 8), 256, 0, stream>>>(
            xbf, Bt, b_iou, b_f, hbuf, cbuf, n, lvl);
    }
    for (int lvl = 6; lvl >= 4; --lvl) {                    // n = 64, 32, 16
        const int n = 1 << lvl;
        gemm_level<<<dim3((Bb * n) / 128, 8), 256, 0, stream>>>(
            xbf, Bt, b_iou, b_f, hbuf, cbuf, n, lvl);
    }
    for (int lvl = 3; lvl >= 0; --lvl) {                    // n = 8 .. 1
        const int n = 1 << lvl;
        gemm_small<<<dim3(1, 8), 256, 0, stream>>>(
            xbf, Bt, b_iou, b_f, hbuf, cbuf, n, lvl);
    }
    out_kernel<<<Bb, 256, 0, stream>>>(hbuf, cbuf, out);
}

// Round 5
// 981.507 us; speedup vs baseline: 4.4275x; 1.0697x over previous
//
#include <hip/hip_runtime.h>
#include <math.h>

// ChildSumTreeLSTM, round 5.
// - 1D swizzled grids: bx=idx>>3, by=idx&7 -> the 8 N-sibling blocks of an
//   A-tile run temporally adjacent -> A fetched once, L3-hits for the rest.
// - xbf holds ALL of x in bf16 (identity heap layout); leaf A staging is now
//   global_load_lds like the levels.
// - h/c stored in even/odd level arenas, j-indexed: GEMM row m's children
//   are rows 2m, 2m+1 of the child arena (batch-independent).
// Bt [1280][768] K-major, gate-interleaved cols (col'=80q+16g+r,
// g in {i,o,u,f1,f2}); XOR-swizzled LDS; h bf16, c fp32.

#define Bb 8
#define Lleaf 16384
#define Nn 32767
#define Dd 256

typedef __attribute__((ext_vector_type(8))) short short8;
typedef __attribute__((ext_vector_type(4))) float float4v;

__device__ __forceinline__ float sigf(float x) {
    return __builtin_amdgcn_rcpf(1.0f + __expf(-x));
}
__device__ __forceinline__ float tanh_fast(float x) {
    return fmaf(2.0f, sigf(2.0f * x), -1.0f);
}
__device__ __forceinline__ unsigned short f2bf(float f) {
    unsigned int u = __float_as_uint(f);
    u = (u + 0x7FFFu + ((u >> 16) & 1u)) >> 16;   // RTNE, finite inputs
    return (unsigned short)u;
}
__device__ __forceinline__ float bf2f(unsigned short h) {
    return __uint_as_float(((unsigned int)h) << 16);
}
__device__ __forceinline__ void load_lds16(const void* g, void* l) {
    __builtin_amdgcn_global_load_lds(
        (const __attribute__((address_space(1))) unsigned int*)g,
        (__attribute__((address_space(3))) unsigned int*)l, 16, 0, 0);
}

// ---------------- x fp32 -> bf16 (identity layout, all nodes) --------------
__global__ __launch_bounds__(256) void xcast(
    const float* __restrict__ x, unsigned short* __restrict__ xbf)
{
    const int base = (blockIdx.x * 256 + threadIdx.x) * 8;   // < 8*Nn*256
    const float4* p = (const float4*)(x + base);
    const float4 f0 = p[0], f1 = p[1];
    union { unsigned short us[8]; uint4 v; } pk;
    pk.us[0] = f2bf(f0.x); pk.us[1] = f2bf(f0.y);
    pk.us[2] = f2bf(f0.z); pk.us[3] = f2bf(f0.w);
    pk.us[4] = f2bf(f1.x); pk.us[5] = f2bf(f1.y);
    pk.us[6] = f2bf(f1.z); pk.us[7] = f2bf(f1.w);
    *(uint4*)(xbf + base) = pk.v;
}

// ---------------- weight packing (once per call, ~2 MB) --------------------
__global__ __launch_bounds__(256) void pack_internal(
    const float* __restrict__ W_iou, const float* __restrict__ U_iou,
    const float* __restrict__ W_f,   const float* __restrict__ U_f,
    unsigned short* __restrict__ Bt)
{
    const int idx = blockIdx.x * 256 + threadIdx.x;      // < 1280*768
    const int col = idx / 768, k = idx - col * 768;
    const int q = col / 80, rem = col - q * 80;
    const int g = rem >> 4, r = rem & 15;
    const int d = (q << 4) + r;
    const int seg = k >> 8, kk = k & 255;
    float val;
    if (g < 3) {
        val = (seg == 0) ? W_iou[kk * 768 + g * 256 + d]
                         : U_iou[kk * 768 + g * 256 + d];
    } else if (seg == 0) {
        val = W_f[kk * 256 + d];
    } else if (seg == 1) {
        val = (g == 3) ? U_f[kk * 256 + d] : 0.0f;
    } else {
        val = (g == 4) ? U_f[kk * 256 + d] : 0.0f;
    }
    Bt[idx] = f2bf(val);
}

__global__ __launch_bounds__(256) void pack_leaf(
    const float* __restrict__ W_iou, unsigned short* __restrict__ Btl)
{
    const int idx = blockIdx.x * 256 + threadIdx.x;      // < 768*256
    const int col = idx >> 8, k = idx & 255;
    const int q = col / 48, rem = col - q * 48;
    const int g = rem >> 4, r = rem & 15;
    const int d = (q << 4) + r;
    Btl[idx] = f2bf(W_iou[k * 768 + g * 256 + d]);
}

// ---------------- big internal levels (n >= 128): uniform batch ------------
// 1D grid: (B*n/128)*8; bx = idx>>3, by = idx&7.
__global__ __launch_bounds__(256, 3) void gemm_level_big(
    const unsigned short* __restrict__ xbf, const unsigned short* __restrict__ Bt,
    const float* __restrict__ b_iou, const float* __restrict__ b_f,
    unsigned short* __restrict__ h_out, float* __restrict__ c_out,
    const unsigned short* __restrict__ h_ch, const float* __restrict__ c_ch,
    int n, int lvl)
{
    __shared__ unsigned short Alds[128 * 64];   // 16 KB, swizzled
    __shared__ unsigned short Blds[160 * 64];   // 20 KB, swizzled
    const int tid  = threadIdx.x;
    const int wave = tid >> 6, lane = tid & 63;
    const int l16  = lane & 15, q4 = lane >> 4;
    const int bx   = blockIdx.x >> 3, by = blockIdx.x & 7;
    const int m0   = bx * 128;
    const int n0   = by * 160;
    const int lr   = lane >> 3;                 // row-in-group 0..7
    const int lp   = (lane & 7) ^ lr;           // swizzled k-part

    // whole tile in one batch (n >= 128); heap x-node of row m0+r = xr0 + r
    const int b   = m0 >> lvl;
    const int xr0 = m0 + (n - 1) + b * (Nn - n);

    float4v acc[2][10];
    #pragma unroll
    for (int qq = 0; qq < 2; ++qq) {
        const int d = ((by * 2 + qq) << 4) + l16;
        float bv0 = b_iou[d], bv1 = b_iou[256 + d], bv2 = b_iou[512 + d];
        float bv3 = b_f[d];
        float bv[5] = {bv0, bv1, bv2, bv3, bv3};
        #pragma unroll
        for (int g = 0; g < 5; ++g) {
            float4v v; v[0] = bv[g]; v[1] = bv[g]; v[2] = bv[g]; v[3] = bv[g];
            acc[0][qq * 5 + g] = v; acc[1][qq * 5 + g] = v;
        }
    }

    for (int kk = 0; kk < 12; ++kk) {          // segs: 0-3 x, 4-7 h1, 8-11 h2
        __syncthreads();
        #pragma unroll
        for (int it = 0; it < 4; ++it) {        // stage A
            const int g = it * 4 + wave;       // 0..15
            const int r = g * 8 + lr;
            const unsigned short* src;
            if (kk < 4) {
                src = xbf + (((xr0 + r) << 8) + kk * 64 + lp * 8);
            } else {
                const int sel = (kk >= 8) ? 1 : 0;
                src = h_ch + (((2 * (m0 + r) + sel) << 8) + ((kk - 4) & 3) * 64 + lp * 8);
            }
            load_lds16(src, &Alds[g * 512]);
        }
        #pragma unroll
        for (int it = 0; it < 5; ++it) {        // stage B
            const int g = it * 4 + wave;       // 0..19
            const int row = g * 8 + lr;
            load_lds16(Bt + ((n0 + row) * 768 + kk * 64 + lp * 8), &Blds[g * 512]);
        }
        __syncthreads();
        #pragma unroll
        for (int ks = 0; ks < 2; ++ks) {
            const int pa = ks * 4 + q4;
            const int sw = (pa ^ (l16 & 7)) * 8;
            const short8 a0 = *(const short8*)&Alds[(wave * 32 + l16) * 64 + sw];
            const short8 a1 = *(const short8*)&Alds[(wave * 32 + 16 + l16) * 64 + sw];
            #pragma unroll
            for (int ni = 0; ni < 10; ++ni) {
                const short8 bf = *(const short8*)&Blds[(ni * 16 + l16) * 64 + sw];
                acc[0][ni] = __builtin_amdgcn_mfma_f32_16x16x32_bf16(a0, bf, acc[0][ni], 0, 0, 0);
                acc[1][ni] = __builtin_amdgcn_mfma_f32_16x16x32_bf16(a1, bf, acc[1][ni], 0, 0, 0);
            }
        }
    }

    #pragma unroll
    for (int mi = 0; mi < 2; ++mi) {
        #pragma unroll
        for (int reg = 0; reg < 4; ++reg) {
            const int row_l = wave * 32 + mi * 16 + (q4 << 2) + reg;
            const int m = m0 + row_l;
            const int cbase = (2 * m) << 8;
            const int obase = m << 8;
            #pragma unroll
            for (int qq = 0; qq < 2; ++qq) {
                const int d = ((by * 2 + qq) << 4) + l16;
                const float i_ = acc[mi][qq * 5 + 0][reg];
                const float o_ = acc[mi][qq * 5 + 1][reg];
                const float u_ = acc[mi][qq * 5 + 2][reg];
                const float f1 = acc[mi][qq * 5 + 3][reg];
                const float f2 = acc[mi][qq * 5 + 4][reg];
                const float c1 = c_ch[cbase + d];
                const float c2 = c_ch[cbase + 256 + d];
                const float c = sigf(i_) * tanh_fast(u_) + sigf(f1) * c1 + sigf(f2) * c2;
                const float h = sigf(o_) * tanh_fast(c);
                c_out[obase + d] = c;
                h_out[obase + d] = f2bf(h);
            }
        }
    }
}

// ---------------- generic internal level (lvl 6..4) ------------------------
__global__ __launch_bounds__(256) void gemm_level(
    const unsigned short* __restrict__ xbf, const unsigned short* __restrict__ Bt,
    const float* __restrict__ b_iou, const float* __restrict__ b_f,
    unsigned short* __restrict__ h_out, float* __restrict__ c_out,
    const unsigned short* __restrict__ h_ch, const float* __restrict__ c_ch,
    int n, int lvl)
{
    __shared__ unsigned short Alds[128 * 64];
    __shared__ unsigned short Blds[160 * 64];
    const int tid  = threadIdx.x;
    const int wave = tid >> 6, lane = tid & 63;
    const int l16  = lane & 15, q4 = lane >> 4;
    const int m0   = blockIdx.x * 128;
    const int n0   = blockIdx.y * 160;
    const int lr   = lane >> 3;
    const int lp   = (lane & 7) ^ lr;

    float4v acc[2][10];
    #pragma unroll
    for (int qq = 0; qq < 2; ++qq) {
        const int d = ((blockIdx.y * 2 + qq) << 4) + l16;
        float bv0 = b_iou[d], bv1 = b_iou[256 + d], bv2 = b_iou[512 + d];
        float bv3 = b_f[d];
        float bv[5] = {bv0, bv1, bv2, bv3, bv3};
        #pragma unroll
        for (int g = 0; g < 5; ++g) {
            float4v v; v[0] = bv[g]; v[1] = bv[g]; v[2] = bv[g]; v[3] = bv[g];
            acc[0][qq * 5 + g] = v; acc[1][qq * 5 + g] = v;
        }
    }

    for (int kk = 0; kk < 12; ++kk) {
        __syncthreads();
        #pragma unroll
        for (int it = 0; it < 4; ++it) {
            const int g = it * 4 + wave;
            const int r = g * 8 + lr;
            const int m = m0 + r;
            const unsigned short* src;
            if (kk < 4) {
                const int b = m >> lvl;
                src = xbf + (((m + (n - 1) + b * (Nn - n)) << 8) + kk * 64 + lp * 8);
            } else {
                const int sel = (kk >= 8) ? 1 : 0;
                src = h_ch + (((2 * m + sel) << 8) + ((kk - 4) & 3) * 64 + lp * 8);
            }
            load_lds16(src, &Alds[g * 512]);
        }
        #pragma unroll
        for (int it = 0; it < 5; ++it) {
            const int g = it * 4 + wave;
            const int row = g * 8 + lr;
            load_lds16(Bt + ((n0 + row) * 768 + kk * 64 + lp * 8), &Blds[g * 512]);
        }
        __syncthreads();
        #pragma unroll
        for (int ks = 0; ks < 2; ++ks) {
            const int pa = ks * 4 + q4;
            const int sw = (pa ^ (l16 & 7)) * 8;
            const short8 a0 = *(const short8*)&Alds[(wave * 32 + l16) * 64 + sw];
            const short8 a1 = *(const short8*)&Alds[(wave * 32 + 16 + l16) * 64 + sw];
            #pragma unroll
            for (int ni = 0; ni < 10; ++ni) {
                const short8 bf = *(const short8*)&Blds[(ni * 16 + l16) * 64 + sw];
                acc[0][ni] = __builtin_amdgcn_mfma_f32_16x16x32_bf16(a0, bf, acc[0][ni], 0, 0, 0);
                acc[1][ni] = __builtin_amdgcn_mfma_f32_16x16x32_bf16(a1, bf, acc[1][ni], 0, 0, 0);
            }
        }
    }

    #pragma unroll
    for (int mi = 0; mi < 2; ++mi) {
        #pragma unroll
        for (int reg = 0; reg < 4; ++reg) {
            const int row_l = wave * 32 + mi * 16 + (q4 << 2) + reg;
            const int m = m0 + row_l;
            const int cbase = (2 * m) << 8;
            const int obase = m << 8;
            #pragma unroll
            for (int qq = 0; qq < 2; ++qq) {
                const int d = ((blockIdx.y * 2 + qq) << 4) + l16;
                const float i_ = acc[mi][qq * 5 + 0][reg];
                const float o_ = acc[mi][qq * 5 + 1][reg];
                const float u_ = acc[mi][qq * 5 + 2][reg];
                const float f1 = acc[mi][qq * 5 + 3][reg];
                const float f2 = acc[mi][qq * 5 + 4][reg];
                const float c1 = c_ch[cbase + d];
                const float c2 = c_ch[cbase + 256 + d];
                const float c = sigf(i_) * tanh_fast(u_) + sigf(f1) * c1 + sigf(f2) * c2;
                const float h = sigf(o_) * tanh_fast(c);
                c_out[obase + d] = c;
                h_out[obase + d] = f2bf(h);
            }
        }
    }
}

// ---------------- tiny levels (n <= 8): M=64 MFMA, clamp+guard -------------
__global__ __launch_bounds__(256) void gemm_small(
    const unsigned short* __restrict__ xbf, const unsigned short* __restrict__ Bt,
    const float* __restrict__ b_iou, const float* __restrict__ b_f,
    unsigned short* __restrict__ h_out, float* __restrict__ c_out,
    const unsigned short* __restrict__ h_ch, const float* __restrict__ c_ch,
    int n, int lvl)
{
    __shared__ unsigned short Alds[64 * 64];    // 8 KB
    __shared__ unsigned short Blds[160 * 64];   // 20 KB
    const int tid  = threadIdx.x;
    const int wave = tid >> 6, lane = tid & 63;
    const int l16  = lane & 15, q4 = lane >> 4;
    const int n0   = blockIdx.y * 160;
    const int lr   = lane >> 3;
    const int lp   = (lane & 7) ^ lr;
    const int rmax = 8 * n - 1;

    float4v acc[10];
    #pragma unroll
    for (int qq = 0; qq < 2; ++qq) {
        const int d = ((blockIdx.y * 2 + qq) << 4) + l16;
        float bv0 = b_iou[d], bv1 = b_iou[256 + d], bv2 = b_iou[512 + d];
        float bv3 = b_f[d];
        float bv[5] = {bv0, bv1, bv2, bv3, bv3};
        #pragma unroll
        for (int g = 0; g < 5; ++g) {
            float4v v; v[0] = bv[g]; v[1] = bv[g]; v[2] = bv[g]; v[3] = bv[g];
            acc[qq * 5 + g] = v;
        }
    }

    for (int kk = 0; kk < 12; ++kk) {
        __syncthreads();
        #pragma unroll
        for (int it = 0; it < 2; ++it) {        // stage A: 8 row-groups
            const int g = it * 4 + wave;       // 0..7
            const int r = g * 8 + lr;
            const int m = (r > rmax) ? rmax : r;
            const unsigned short* src;
            if (kk < 4) {
                const int b = m >> lvl;
                src = xbf + (((m + (n - 1) + b * (Nn - n)) << 8) + kk * 64 + lp * 8);
            } else {
                const int sel = (kk >= 8) ? 1 : 0;
                src = h_ch + (((2 * m + sel) << 8) + ((kk - 4) & 3) * 64 + lp * 8);
            }
            load_lds16(src, &Alds[g * 512]);
        }
        #pragma unroll
        for (int it = 0; it < 5; ++it) {        // stage B
            const int g = it * 4 + wave;
            const int row = g * 8 + lr;
            load_lds16(Bt + ((n0 + row) * 768 + kk * 64 + lp * 8), &Blds[g * 512]);
        }
        __syncthreads();
        #pragma unroll
        for (int ks = 0; ks < 2; ++ks) {
            const int pa = ks * 4 + q4;
            const int sw = (pa ^ (l16 & 7)) * 8;
            const short8 a0 = *(const short8*)&Alds[(wave * 16 + l16) * 64 + sw];
            #pragma unroll
            for (int ni = 0; ni < 10; ++ni) {
                const short8 bf = *(const short8*)&Blds[(ni * 16 + l16) * 64 + sw];
                acc[ni] = __builtin_amdgcn_mfma_f32_16x16x32_bf16(a0, bf, acc[ni], 0, 0, 0);
            }
        }
    }

    #pragma unroll
    for (int reg = 0; reg < 4; ++reg) {
        const int row_l = wave * 16 + (q4 << 2) + reg;
        const int m = (row_l > rmax) ? rmax : row_l;
        const bool valid = (row_l <= rmax);
        const int cbase = (2 * m) << 8;
        const int obase = m << 8;
        #pragma unroll
        for (int qq = 0; qq < 2; ++qq) {
            const int d = ((blockIdx.y * 2 + qq) << 4) + l16;
            const float i_ = acc[qq * 5 + 0][reg];
            const float o_ = acc[qq * 5 + 1][reg];
            const float u_ = acc[qq * 5 + 2][reg];
            const float f1 = acc[qq * 5 + 3][reg];
            const float f2 = acc[qq * 5 + 4][reg];
            const float c1 = c_ch[cbase + d];
            const float c2 = c_ch[cbase + 256 + d];
            const float c = sigf(i_) * tanh_fast(u_) + sigf(f1) * c1 + sigf(f2) * c2;
            const float h = sigf(o_) * tanh_fast(c);
            if (valid) {
                c_out[obase + d] = c;
                h_out[obase + d] = f2bf(h);
            }
        }
    }
}

// ---------------- leaf MFMA GEMM -------------------------------------------
// 1D grid (1024*8); tile M=128, N=96, K=256, BK=64; A via global_load_lds.
__global__ __launch_bounds__(256, 3) void gemm_leaf(
    const unsigned short* __restrict__ xbf, const unsigned short* __restrict__ Btl,
    const float* __restrict__ b_iou,
    unsigned short* __restrict__ h_out, float* __restrict__ c_out)
{
    __shared__ unsigned short Alds[128 * 64];   // 16 KB
    __shared__ unsigned short Blds[96 * 64];    // 12 KB
    const int tid  = threadIdx.x;
    const int wave = tid >> 6, lane = tid & 63;
    const int l16  = lane & 15, q4 = lane >> 4;
    const int bx   = blockIdx.x >> 3, by = blockIdx.x & 7;
    const int m0   = bx * 128;
    const int n0   = by * 96;
    const int lr   = lane >> 3;
    const int lp   = (lane & 7) ^ lr;

    const int b   = m0 >> 14;
    const int xr0 = m0 + (Lleaf - 1) + b * (Nn - Lleaf);

    float4v acc[2][6];
    #pragma unroll
    for (int qq = 0; qq < 2; ++qq) {
        const int d = ((by * 2 + qq) << 4) + l16;
        float bv[3] = {b_iou[d], b_iou[256 + d], b_iou[512 + d]};
        #pragma unroll
        for (int g = 0; g < 3; ++g) {
            float4v v; v[0] = bv[g]; v[1] = bv[g]; v[2] = bv[g]; v[3] = bv[g];
            acc[0][qq * 3 + g] = v; acc[1][qq * 3 + g] = v;
        }
    }

    for (int kk = 0; kk < 4; ++kk) {
        __syncthreads();
        #pragma unroll
        for (int it = 0; it < 4; ++it) {        // stage A: 16 row-groups
            const int g = it * 4 + wave;
            const int r = g * 8 + lr;
            load_lds16(xbf + (((xr0 + r) << 8) + kk * 64 + lp * 8), &Alds[g * 512]);
        }
        #pragma unroll
        for (int it = 0; it < 3; ++it) {        // stage B: 12 row-groups
            const int g = it * 4 + wave;        // 0..11
            const int row = g * 8 + lr;
            load_lds16(Btl + ((n0 + row) * 256 + kk * 64 + lp * 8), &Blds[g * 512]);
        }
        __syncthreads();
        #pragma unroll
        for (int ks = 0; ks < 2; ++ks) {
            const int pa = ks * 4 + q4;
            const int sw = (pa ^ (l16 & 7)) * 8;
            const short8 a0 = *(const short8*)&Alds[(wave * 32 + l16) * 64 + sw];
            const short8 a1 = *(const short8*)&Alds[(wave * 32 + 16 + l16) * 64 + sw];
            #pragma unroll
            for (int ni = 0; ni < 6; ++ni) {
                const short8 bf = *(const short8*)&Blds[(ni * 16 + l16) * 64 + sw];
                acc[0][ni] = __builtin_amdgcn_mfma_f32_16x16x32_bf16(a0, bf, acc[0][ni], 0, 0, 0);
                acc[1][ni] = __builtin_amdgcn_mfma_f32_16x16x32_bf16(a1, bf, acc[1][ni], 0, 0, 0);
            }
        }
    }

    #pragma unroll
    for (int mi = 0; mi < 2; ++mi) {
        #pragma unroll
        for (int reg = 0; reg < 4; ++reg) {
            const int row_l = wave * 32 + mi * 16 + (q4 << 2) + reg;
            const int obase = (m0 + row_l) << 8;
            #pragma unroll
            for (int qq = 0; qq < 2; ++qq) {
                const int d = ((by * 2 + qq) << 4) + l16;
                const float i_ = acc[mi][qq * 3 + 0][reg];
                const float o_ = acc[mi][qq * 3 + 1][reg];
                const float u_ = acc[mi][qq * 3 + 2][reg];
                const float c = sigf(i_) * tanh_fast(u_);
                const float h = sigf(o_) * tanh_fast(c);
                c_out[obase + d] = c;
                h_out[obase + d] = f2bf(h);
            }
        }
    }
}

__global__ __launch_bounds__(256) void out_kernel(
    const unsigned short* __restrict__ h_root, const float* __restrict__ c_root,
    float* __restrict__ out)
{
    const int t = threadIdx.x;
    const int b = blockIdx.x;
    out[b * 512 + t]       = bf2f(h_root[(b << 8) + t]);   // root row = b
    out[b * 512 + 256 + t] = c_root[(b << 8) + t];
}

extern "C" void kernel_launch(void* const* d_in, const int* in_sizes, int n_in,
                              void* d_out, int out_size, void* d_ws, size_t ws_size,
                              hipStream_t stream) {
    const float* x     = (const float*)d_in[0];
    const float* W_iou = (const float*)d_in[1];
    const float* b_iou = (const float*)d_in[2];
    const float* U_iou = (const float*)d_in[3];
    const float* W_f   = (const float*)d_in[4];
    const float* b_f   = (const float*)d_in[5];
    const float* U_f   = (const float*)d_in[6];
    float* out = (float*)d_out;

    // arenas: E = even levels (leaf=14,12,..,0) rows B*16384; O = odd, B*8192
    char* p = (char*)d_ws;
    unsigned short* xbf = (unsigned short*)p;  p += (size_t)Bb * Nn * Dd * 2;       // 134 MB
    float* cE = (float*)p;                     p += (size_t)Bb * Lleaf * Dd * 4;    // 134 MB
    float* cO = (float*)p;                     p += (size_t)Bb * (Lleaf/2) * Dd * 4;// 67 MB
    unsigned short* hE = (unsigned short*)p;   p += (size_t)Bb * Lleaf * Dd * 2;    // 67 MB
    unsigned short* hO = (unsigned short*)p;   p += (size_t)Bb * (Lleaf/2) * Dd * 2;// 33.5 MB
    unsigned short* Bt  = (unsigned short*)p;  p += 1280 * 768 * 2;
    unsigned short* Btl = (unsigned short*)p;

    xcast<<<(Bb * Nn * Dd) / (256 * 8), 256, 0, stream>>>(x, xbf);
    pack_internal<<<(1280 * 768) / 256, 256, 0, stream>>>(W_iou, U_iou, W_f, U_f, Bt);
    pack_leaf<<<(768 * 256) / 256, 256, 0, stream>>>(W_iou, Btl);

    // leaf (lvl 14, even) -> E
    gemm_leaf<<<(Bb * Lleaf / 128) * 8, 256, 0, stream>>>(xbf, Btl, b_iou, hE, cE);

    for (int lvl = 13; lvl >= 7; --lvl) {                   // n = 8192 .. 128
        const int n = 1 << lvl;
        unsigned short* ho = (lvl & 1) ? hO : hE;  float* co = (lvl & 1) ? cO : cE;
        unsigned short* hc = (lvl & 1) ? hE : hO;  float* cc = (lvl & 1) ? cE : cO;
        gemm_level_big<<<(Bb * n / 128) * 8, 256, 0, stream>>>(
            xbf, Bt, b_iou, b_f, ho, co, hc, cc, n, lvl);
    }
    for (int lvl = 6; lvl >= 4; --lvl) {                    // n = 64, 32, 16
        const int n = 1 << lvl;
        unsigned short* ho = (lvl & 1) ? hO : hE;  float* co = (lvl & 1) ? cO : cE;
        unsigned short* hc = (lvl & 1) ? hE : hO;  float* cc = (lvl & 1) ? cE : cO;
        gemm_level<<<dim3(Bb * n / 128, 8), 256, 0, stream>>>(
            xbf, Bt, b_iou, b_f, ho, co, hc, cc, n, lvl);
    }
    for (int lvl = 3; lvl >= 0; --lvl) {                    // n = 8 .. 1
        const int n = 1 << lvl;
        unsigned short* ho = (lvl & 1) ? hO : hE;  float* co = (lvl & 1) ? cO : cE;
        unsigned short* hc = (lvl & 1) ? hE : hO;  float* cc = (lvl & 1) ? cE : cO;
        gemm_small<<<dim3(1, 8), 256, 0, stream>>>(
            xbf, Bt, b_iou, b_f, ho, co, hc, cc, n, lvl);
    }
    out_kernel<<<Bb, 256, 0, stream>>>(hE, cE, out);        // lvl 0 is even
}